// Round 2
// baseline (734.496 us; speedup 1.0000x reference)
//
#include <hip/hip_runtime.h>
#include <hip/hip_bf16.h>

typedef float f32x4 __attribute__((ext_vector_type(4)));
typedef short s16x8 __attribute__((ext_vector_type(8)));
typedef unsigned int u32x4 __attribute__((ext_vector_type(4)));

#define F_IN 256
#define F_OUT 64
#define KSPLIT 8

static __device__ __forceinline__ short f2bf(float f){  // RTNE
  union { float f; unsigned u; } x; x.f = f;
  unsigned r = (x.u + 0x7FFFu + ((x.u >> 16) & 1u)) >> 16;
  return (short)r;
}

// pack 2 f32 -> 2 bf16 by truncation (bias cancels in L2-normalize downstream)
static __device__ __forceinline__ unsigned pack_trunc(float f0, float f1){
  return (__float_as_uint(f0) >> 16) | (__float_as_uint(f1) & 0xFFFF0000u);
}

union FragU { u32x4 u; s16x8 s; };

// ---------------- degree / CSR build ----------------

__global__ void hist_kernel(const int* __restrict__ ei, int E, int* __restrict__ deg,
                            int* __restrict__ counts){
  int e = blockIdx.x * blockDim.x + threadIdx.x;
  if (e >= E) return;
  int r = ei[e], c = ei[E + e];
  if (r != c) atomicAdd(&deg[r], 1);
  atomicAdd(&counts[c], 1);
}

__global__ void dis_kernel(const int* __restrict__ deg, float* __restrict__ dis,
                           float* __restrict__ selfnorm, int n){
  int i = blockIdx.x * blockDim.x + threadIdx.x;
  if (i >= n) return;
  float d = (float)(deg[i] + 1);   // +1: appended self-loop
  dis[i] = rsqrtf(d);
  selfnorm[i] = 1.0f / d;
}

__global__ __launch_bounds__(1024) void scan_kernel(const int* __restrict__ counts,
                                                    int* __restrict__ offsets,
                                                    int* __restrict__ cursors, int n){
  const int C = 10;
  __shared__ int lds[1024];
  int tid = threadIdx.x;
  int base = tid * C;
  int s = 0;
  for (int i = 0; i < C; ++i){ int idx = base + i; if (idx < n) s += counts[idx]; }
  lds[tid] = s; __syncthreads();
  for (int off = 1; off < 1024; off <<= 1){
    int add = (tid >= off) ? lds[tid - off] : 0;
    __syncthreads();
    lds[tid] += add;
    __syncthreads();
  }
  int run = lds[tid] - s;
  for (int i = 0; i < C; ++i){
    int idx = base + i;
    if (idx < n){ offsets[idx] = run; cursors[idx] = run; run += counts[idx]; }
  }
  if (tid == 1023) offsets[n] = lds[1023];
}

__global__ void fill_kernel(const int* __restrict__ ei, int E, const float* __restrict__ dis,
                            int* __restrict__ cursors, int* __restrict__ csr_row,
                            float* __restrict__ csr_norm){
  int e = blockIdx.x * blockDim.x + threadIdx.x;
  if (e >= E) return;
  int r = ei[e], c = ei[E + e];
  int pos = atomicAdd(&cursors[c], 1);
  csr_row[pos] = r;
  csr_norm[pos] = (r == c) ? 0.0f : dis[r] * dis[c];
}

// ---------------- f32 -> bf16 cast (RTNE), 8 elems/thread ----------------

__global__ void cast_kernel(const float* __restrict__ src, short* __restrict__ dst, int n8){
  int idx = blockIdx.x * blockDim.x + threadIdx.x;
  if (idx >= n8) return;
  const f32x4* p = (const f32x4*)src + (size_t)idx * 2;
  f32x4 a = p[0], b = p[1];
  s16x8 r = { f2bf(a[0]), f2bf(a[1]), f2bf(a[2]), f2bf(a[3]),
              f2bf(b[0]), f2bf(b[1]), f2bf(b[2]), f2bf(b[3]) };
  ((s16x8*)dst)[idx] = r;
}

// W [1280,64] f32 -> WT [5][64][256] bf16 (transposed per slab)
__global__ void wt_kernel(const float* __restrict__ W, short* __restrict__ WT){
  int idx = blockIdx.x * blockDim.x + threadIdx.x;
  if (idx >= 5 * 64 * 256) return;
  int k = idx & 255, c = (idx >> 8) & 63, by = idx >> 14;
  WT[idx] = f2bf(W[(size_t)(by * 256 + k) * 64 + c]);
}

// ---------------- feature GEMM (bf16 MFMA, direct fragments) ----------------
// Y[by][M][64] = Xb @ WT[by]^T ; grid (M/16, 5), 64 threads (1 wave)

__global__ __launch_bounds__(64) void fgemm_kernel(const short* __restrict__ Xb,
                                                   const short* __restrict__ WT,
                                                   float* __restrict__ Y, int M){
  int l = threadIdx.x, lr = l & 15, g = l >> 4;
  int row0 = blockIdx.x * 16, by = blockIdx.y;
  const s16x8* ap = (const s16x8*)(Xb + (size_t)(row0 + lr) * F_IN + g * 8);
  const s16x8* bp[4];
  #pragma unroll
  for (int ct = 0; ct < 4; ++ct)
    bp[ct] = (const s16x8*)(WT + ((size_t)by * 64 + ct * 16 + lr) * F_IN + g * 8);
  f32x4 acc[4];
  #pragma unroll
  for (int ct = 0; ct < 4; ++ct) acc[ct] = (f32x4){0,0,0,0};
  #pragma unroll
  for (int it = 0; it < 8; ++it){
    s16x8 af = ap[it * 4];
    #pragma unroll
    for (int ct = 0; ct < 4; ++ct)
      acc[ct] = __builtin_amdgcn_mfma_f32_16x16x32_bf16(af, bp[ct][it * 4], acc[ct], 0, 0, 0);
  }
  float* yp = Y + (size_t)by * M * 64;
  #pragma unroll
  for (int ct = 0; ct < 4; ++ct)
    #pragma unroll
    for (int i = 0; i < 4; ++i)
      yp[(size_t)(row0 + g * 4 + i) * 64 + ct * 16 + lr] = acc[ct][i];
}

// ---------------- sparse propagate: tout = Yk + A * tin ----------------

__global__ __launch_bounds__(256) void gather_kernel(const float* __restrict__ Yk,
    const float* __restrict__ tin, const int* __restrict__ offsets,
    const int* __restrict__ csr_row, const float* __restrict__ csr_norm,
    const float* __restrict__ selfnorm, float* __restrict__ tout, int n){
  int wid = threadIdx.x >> 6, lane = threadIdx.x & 63;
  int node = blockIdx.x * 4 + wid;
  if (node >= n) return;
  int e0 = offsets[node], e1 = offsets[node + 1];
  float acc = Yk[(size_t)node * 64 + lane] + selfnorm[node] * tin[(size_t)node * 64 + lane];
  int i = e0;
  for (; i + 4 <= e1; i += 4){
    int r0 = csr_row[i], r1 = csr_row[i+1], r2 = csr_row[i+2], r3 = csr_row[i+3];
    float w0 = csr_norm[i], w1 = csr_norm[i+1], w2 = csr_norm[i+2], w3 = csr_norm[i+3];
    acc += w0 * tin[(size_t)r0 * 64 + lane];
    acc += w1 * tin[(size_t)r1 * 64 + lane];
    acc += w2 * tin[(size_t)r2 * 64 + lane];
    acc += w3 * tin[(size_t)r3 * 64 + lane];
  }
  for (; i < e1; ++i) acc += csr_norm[i] * tin[(size_t)csr_row[i] * 64 + lane];
  tout[(size_t)node * 64 + lane] = acc;
}

// ---------------- relu + bf16 transpose cast ----------------

__global__ void relu_cast_kernel(const float* __restrict__ h, float* __restrict__ outf,
                                 short* __restrict__ embBT, int coloff, int n){
  int idx = blockIdx.x * blockDim.x + threadIdx.x;
  if (idx >= n * 64) return;
  int node = idx >> 6, f = idx & 63;
  float v = h[idx]; v = v > 0.0f ? v : 0.0f;
  outf[idx] = v;
  embBT[(size_t)(coloff + f) * n + node] = f2bf(v);
}

// ---------------- readout GEMM: vsum[ks][n][128] partial = mask @ embBT^T ----------------
// Barrier-free, LDS-free: 1 wave = 16 rows x 128 cols; K split 8 ways over blockIdx.y.
// A fragments: f32 mask loads, truncate-pack to bf16 in-register.
// B fragments: direct s16x8 loads from L2-resident embBT.

__global__ __launch_bounds__(64) void readout_kernel(const float* __restrict__ mask,
    const short* __restrict__ embBT, float* __restrict__ vsum, int n){
  int l = threadIdx.x, lr = l & 15, g = l >> 4;
  int row0 = blockIdx.x * 16;
  int ks = blockIdx.y;
  int kbeg = ks * 1248;
  int kend = (ks == KSPLIT - 1) ? n : kbeg + 1248;
  int klen = kend - kbeg;
  int nfull = klen >> 5, rem = klen & 31;   // rem = 16 on last split only

  const f32x4* ap = (const f32x4*)(mask + (size_t)(row0 + lr) * n + kbeg + g * 8);
  const s16x8* bp[8];
  #pragma unroll
  for (int ct = 0; ct < 8; ++ct)
    bp[ct] = (const s16x8*)(embBT + (size_t)(ct * 16 + lr) * n + kbeg + g * 8);

  f32x4 acc[8];
  #pragma unroll
  for (int ct = 0; ct < 8; ++ct) acc[ct] = (f32x4){0,0,0,0};

  #pragma unroll 2
  for (int it = 0; it < nfull; ++it){
    f32x4 a0 = ap[it * 8], a1 = ap[it * 8 + 1];
    FragU af;
    af.u[0] = pack_trunc(a0[0], a0[1]);
    af.u[1] = pack_trunc(a0[2], a0[3]);
    af.u[2] = pack_trunc(a1[0], a1[1]);
    af.u[3] = pack_trunc(a1[2], a1[3]);
    #pragma unroll
    for (int ct = 0; ct < 8; ++ct){
      s16x8 bf = bp[ct][it * 4];
      acc[ct] = __builtin_amdgcn_mfma_f32_16x16x32_bf16(af.s, bf, acc[ct], 0, 0, 0);
    }
  }
  if (rem){
    FragU af; af.u = (u32x4){0,0,0,0};
    s16x8 bf[8];
    s16x8 bz = {0,0,0,0,0,0,0,0};
    #pragma unroll
    for (int ct = 0; ct < 8; ++ct) bf[ct] = bz;
    if (g * 8 < rem){
      f32x4 a0 = ap[nfull * 8], a1 = ap[nfull * 8 + 1];
      af.u[0] = pack_trunc(a0[0], a0[1]);
      af.u[1] = pack_trunc(a0[2], a0[3]);
      af.u[2] = pack_trunc(a1[0], a1[1]);
      af.u[3] = pack_trunc(a1[2], a1[3]);
      #pragma unroll
      for (int ct = 0; ct < 8; ++ct) bf[ct] = bp[ct][nfull * 4];
    }
    #pragma unroll
    for (int ct = 0; ct < 8; ++ct)
      acc[ct] = __builtin_amdgcn_mfma_f32_16x16x32_bf16(af.s, bf[ct], acc[ct], 0, 0, 0);
  }

  float* vs = vsum + (size_t)ks * n * 128;
  #pragma unroll
  for (int ct = 0; ct < 8; ++ct)
    #pragma unroll
    for (int i = 0; i < 4; ++i)
      vs[(size_t)(row0 + g * 4 + i) * 128 + ct * 16 + lr] = acc[ct][i];
}

// ---------------- g = sigmoid(v / ||v||), summing K-split partials ----------------

__global__ __launch_bounds__(256) void gnorm_kernel(const float* __restrict__ vsum,
                                                    float* __restrict__ gbuf, int n){
  int wid = threadIdx.x >> 6, lane = threadIdx.x & 63;
  int node = blockIdx.x * 4 + wid;
  if (node >= n) return;
  size_t stride = (size_t)n * 128;
  float v1 = 0.0f, v2 = 0.0f;
  #pragma unroll
  for (int ks = 0; ks < KSPLIT; ++ks){
    v1 += vsum[ks * stride + (size_t)node * 128 + lane];
    v2 += vsum[ks * stride + (size_t)node * 128 + 64 + lane];
  }
  float s1 = v1 * v1, s2 = v2 * v2;
  for (int off = 32; off >= 1; off >>= 1){
    s1 += __shfl_xor(s1, off);
    s2 += __shfl_xor(s2, off);
  }
  float i1 = v1 / fmaxf(sqrtf(s1), 1e-12f);
  float i2 = v2 / fmaxf(sqrtf(s2), 1e-12f);
  gbuf[(size_t)node * 128 + lane]      = 1.0f / (1.0f + expf(-i1));
  gbuf[(size_t)node * 128 + 64 + lane] = 1.0f / (1.0f + expf(-i2));
}

// ---------------- bilinear discriminator ----------------

__global__ __launch_bounds__(256) void disc_kernel(const float* __restrict__ emb,
    const float* __restrict__ emb_a, const float* __restrict__ gbuf,
    const float* __restrict__ Wb, const float* __restrict__ bptr,
    float* __restrict__ ret, float* __restrict__ reta, int n){
  __shared__ float Wl[64][65];
  int t = threadIdx.x;
  for (int i = t; i < 4096; i += 256) Wl[i >> 6][i & 63] = Wb[i];
  __syncthreads();
  int wid = t >> 6, lane = t & 63;
  int node = blockIdx.x * 4 + wid;
  if (node >= n) return;
  float e1 = emb[(size_t)node * 64 + lane];
  float e2 = emb_a[(size_t)node * 64 + lane];
  float g1 = gbuf[(size_t)node * 128 + lane];
  float g2 = gbuf[(size_t)node * 128 + 64 + lane];
  float u1 = 0.0f, u2 = 0.0f;
  for (int e = 0; e < 64; ++e){
    float wv = Wl[lane][e];
    u1 += wv * __shfl(g1, e);
    u2 += wv * __shfl(g2, e);
  }
  float p1 = e1 * u1, p2 = e2 * u1, p3 = e2 * u2, p4 = e1 * u2;
  for (int off = 32; off >= 1; off >>= 1){
    p1 += __shfl_xor(p1, off); p2 += __shfl_xor(p2, off);
    p3 += __shfl_xor(p3, off); p4 += __shfl_xor(p4, off);
  }
  if (lane == 0){
    float b = bptr[0];
    ret[(size_t)node * 2 + 0]  = p1 + b;
    ret[(size_t)node * 2 + 1]  = p2 + b;
    reta[(size_t)node * 2 + 0] = p3 + b;
    reta[(size_t)node * 2 + 1] = p4 + b;
  }
}

// ---------------- launch ----------------

extern "C" void kernel_launch(void* const* d_in, const int* in_sizes, int n_in,
                              void* d_out, int out_size, void* d_ws, size_t ws_size,
                              hipStream_t stream) {
  const float* feat   = (const float*)d_in[0];
  const float* feat_a = (const float*)d_in[1];
  const int*   ei     = (const int*)d_in[2];
  const float* mask   = (const float*)d_in[3];
  const float* W      = (const float*)d_in[4];
  const float* Wb     = (const float*)d_in[5];
  const float* bsc    = (const float*)d_in[6];
  const int n = in_sizes[0] / F_IN;      // 10000
  const int E = in_sizes[2] / 2;         // 640000
  const size_t sl = (size_t)n * F_OUT;

  float* out  = (float*)d_out;
  float* ret  = out + (size_t)n * F_OUT;
  float* reta = ret + (size_t)n * 2;

  char* wsb = (char*)d_ws;
  size_t off = 0;
  #define WSALLOC(ptr, T, cnt) T* ptr = (T*)(wsb + off); off = (off + sizeof(T)*(size_t)(cnt) + 255) & ~(size_t)255
  WSALLOC(deg, int, n);
  WSALLOC(counts, int, n);
  WSALLOC(offs, int, n + 1);
  WSALLOC(cursors, int, n);
  WSALLOC(dis, float, n);
  WSALLOC(selfnorm, float, n);
  WSALLOC(csr_row, int, E);
  WSALLOC(csr_norm, float, E);
  WSALLOC(featbf, short, (size_t)n * F_IN);
  WSALLOC(featabf, short, (size_t)n * F_IN);
  WSALLOC(WT, short, 5 * 64 * 256);
  WSALLOC(Y,  float, sl * 5);
  WSALLOC(Ya, float, sl * 5);
  WSALLOC(u0, float, sl);
  WSALLOC(u1, float, sl);
  WSALLOC(emb_a, float, sl);
  WSALLOC(embBT, short, (size_t)2 * F_OUT * n);
  WSALLOC(vsum, float, (size_t)n * 128 * KSPLIT);
  WSALLOC(gbuf, float, (size_t)n * 128);
  (void)ws_size; (void)n_in; (void)out_size;

  hipMemsetAsync(deg, 0, (size_t)n * 4, stream);
  hipMemsetAsync(counts, 0, (size_t)n * 4, stream);

  int eb = (E + 255) / 256;
  hist_kernel<<<eb, 256, 0, stream>>>(ei, E, deg, counts);
  dis_kernel<<<(n + 255) / 256, 256, 0, stream>>>(deg, dis, selfnorm, n);
  scan_kernel<<<1, 1024, 0, stream>>>(counts, offs, cursors, n);
  fill_kernel<<<eb, 256, 0, stream>>>(ei, E, dis, cursors, csr_row, csr_norm);

  int n8 = n * F_IN / 8;
  cast_kernel<<<(n8 + 255) / 256, 256, 0, stream>>>(feat,   featbf,  n8);
  cast_kernel<<<(n8 + 255) / 256, 256, 0, stream>>>(feat_a, featabf, n8);
  wt_kernel<<<(5 * 64 * 256 + 255) / 256, 256, 0, stream>>>(W, WT);

  dim3 fg(n / 16, 5);
  fgemm_kernel<<<fg, 64, 0, stream>>>(featbf,  WT, Y,  n);
  fgemm_kernel<<<fg, 64, 0, stream>>>(featabf, WT, Ya, n);

  int gb = (n + 3) / 4;
  gather_kernel<<<gb, 256, 0, stream>>>(Y + 3 * sl, Y + 4 * sl, offs, csr_row, csr_norm, selfnorm, u0, n);
  gather_kernel<<<gb, 256, 0, stream>>>(Y + 2 * sl, u0, offs, csr_row, csr_norm, selfnorm, u1, n);
  gather_kernel<<<gb, 256, 0, stream>>>(Y + 1 * sl, u1, offs, csr_row, csr_norm, selfnorm, u0, n);
  gather_kernel<<<gb, 256, 0, stream>>>(Y + 0 * sl, u0, offs, csr_row, csr_norm, selfnorm, u1, n);
  relu_cast_kernel<<<(n * 64 + 255) / 256, 256, 0, stream>>>(u1, out, embBT, 0, n);
  gather_kernel<<<gb, 256, 0, stream>>>(Ya + 3 * sl, Ya + 4 * sl, offs, csr_row, csr_norm, selfnorm, u0, n);
  gather_kernel<<<gb, 256, 0, stream>>>(Ya + 2 * sl, u0, offs, csr_row, csr_norm, selfnorm, u1, n);
  gather_kernel<<<gb, 256, 0, stream>>>(Ya + 1 * sl, u1, offs, csr_row, csr_norm, selfnorm, u0, n);
  gather_kernel<<<gb, 256, 0, stream>>>(Ya + 0 * sl, u0, offs, csr_row, csr_norm, selfnorm, u1, n);
  relu_cast_kernel<<<(n * 64 + 255) / 256, 256, 0, stream>>>(u1, emb_a, embBT, 64, n);

  readout_kernel<<<dim3(n / 16, KSPLIT), 64, 0, stream>>>(mask, embBT, vsum, n);
  gnorm_kernel<<<gb, 256, 0, stream>>>(vsum, gbuf, n);
  disc_kernel<<<gb, 256, 0, stream>>>(out, emb_a, gbuf, Wb, bsc, ret, reta, n);
}

// Round 3
// 578.328 us; speedup vs baseline: 1.2700x; 1.2700x over previous
//
#include <hip/hip_runtime.h>
#include <hip/hip_bf16.h>

typedef float f32x4 __attribute__((ext_vector_type(4)));
typedef short s16x8 __attribute__((ext_vector_type(8)));
typedef unsigned int u32x4 __attribute__((ext_vector_type(4)));

#define F_IN 256
#define F_OUT 64
#define KSPLIT 8

static __device__ __forceinline__ short f2bf(float f){  // RTNE
  union { float f; unsigned u; } x; x.f = f;
  unsigned r = (x.u + 0x7FFFu + ((x.u >> 16) & 1u)) >> 16;
  return (short)r;
}

static __device__ __forceinline__ unsigned pack_rtne(float f0, float f1){
  return ((unsigned)(unsigned short)f2bf(f0)) | ((unsigned)(unsigned short)f2bf(f1) << 16);
}

// truncation pack (bias cancels in L2-normalize downstream of the mask GEMM)
static __device__ __forceinline__ unsigned pack_trunc(float f0, float f1){
  return (__float_as_uint(f0) >> 16) | (__float_as_uint(f1) & 0xFFFF0000u);
}

union FragU { u32x4 u; s16x8 s; };

// ---------------- degree / CSR build ----------------

__global__ void hist_kernel(const int* __restrict__ ei, int E, int* __restrict__ deg,
                            int* __restrict__ counts){
  int e = blockIdx.x * blockDim.x + threadIdx.x;
  if (e >= E) return;
  int r = ei[e], c = ei[E + e];
  if (r != c) atomicAdd(&deg[r], 1);
  atomicAdd(&counts[c], 1);
}

__global__ void dis_kernel(const int* __restrict__ deg, float* __restrict__ dis,
                           float* __restrict__ selfnorm, int n){
  int i = blockIdx.x * blockDim.x + threadIdx.x;
  if (i >= n) return;
  float d = (float)(deg[i] + 1);   // +1: appended self-loop
  dis[i] = rsqrtf(d);
  selfnorm[i] = 1.0f / d;
}

__global__ __launch_bounds__(1024) void scan_kernel(const int* __restrict__ counts,
                                                    int* __restrict__ offsets,
                                                    int* __restrict__ cursors, int n){
  const int C = 10;
  __shared__ int lds[1024];
  int tid = threadIdx.x;
  int base = tid * C;
  int s = 0;
  for (int i = 0; i < C; ++i){ int idx = base + i; if (idx < n) s += counts[idx]; }
  lds[tid] = s; __syncthreads();
  for (int off = 1; off < 1024; off <<= 1){
    int add = (tid >= off) ? lds[tid - off] : 0;
    __syncthreads();
    lds[tid] += add;
    __syncthreads();
  }
  int run = lds[tid] - s;
  for (int i = 0; i < C; ++i){
    int idx = base + i;
    if (idx < n){ offsets[idx] = run; cursors[idx] = run; run += counts[idx]; }
  }
  if (tid == 1023) offsets[n] = lds[1023];
}

__global__ void fill_kernel(const int* __restrict__ ei, int E, const float* __restrict__ dis,
                            int* __restrict__ cursors, int* __restrict__ csr_row,
                            float* __restrict__ csr_norm){
  int e = blockIdx.x * blockDim.x + threadIdx.x;
  if (e >= E) return;
  int r = ei[e], c = ei[E + e];
  int pos = atomicAdd(&cursors[c], 1);
  csr_row[pos] = r;
  csr_norm[pos] = (r == c) ? 0.0f : dis[r] * dis[c];
}

// W [1280,64] f32 -> WT [5][64][256] bf16 (transposed per slab)
__global__ void wt_kernel(const float* __restrict__ W, short* __restrict__ WT){
  int idx = blockIdx.x * blockDim.x + threadIdx.x;
  if (idx >= 5 * 64 * 256) return;
  int k = idx & 255, c = (idx >> 8) & 63, by = idx >> 14;
  WT[idx] = f2bf(W[(size_t)(by * 256 + k) * 64 + c]);
}

// ---------------- feature GEMM (bf16 MFMA, fused f32->bf16 cast) ----------------
// Yc[by][M][128]: cols [0:64) = feat slab, [64:128) = feat_a slab.
// grid (M/16, 5, 2), 64 threads.

__global__ __launch_bounds__(64) void fgemm_kernel(const float* __restrict__ X0,
                                                   const float* __restrict__ X1,
                                                   const short* __restrict__ WT,
                                                   float* __restrict__ Yc, int M){
  const float* X = blockIdx.z ? X1 : X0;
  int l = threadIdx.x, lr = l & 15, g = l >> 4;
  int row0 = blockIdx.x * 16, by = blockIdx.y;
  const f32x4* ap = (const f32x4*)(X + (size_t)(row0 + lr) * F_IN + g * 8);
  const s16x8* bp[4];
  #pragma unroll
  for (int ct = 0; ct < 4; ++ct)
    bp[ct] = (const s16x8*)(WT + ((size_t)by * 64 + ct * 16 + lr) * F_IN + g * 8);
  f32x4 acc[4];
  #pragma unroll
  for (int ct = 0; ct < 4; ++ct) acc[ct] = (f32x4){0,0,0,0};
  #pragma unroll
  for (int it = 0; it < 8; ++it){
    f32x4 x0 = ap[it * 8], x1 = ap[it * 8 + 1];
    FragU af;
    af.u[0] = pack_rtne(x0[0], x0[1]);
    af.u[1] = pack_rtne(x0[2], x0[3]);
    af.u[2] = pack_rtne(x1[0], x1[1]);
    af.u[3] = pack_rtne(x1[2], x1[3]);
    #pragma unroll
    for (int ct = 0; ct < 4; ++ct)
      acc[ct] = __builtin_amdgcn_mfma_f32_16x16x32_bf16(af.s, bp[ct][it * 4], acc[ct], 0, 0, 0);
  }
  float* yp = Yc + (size_t)by * M * 128 + blockIdx.z * 64;
  #pragma unroll
  for (int ct = 0; ct < 4; ++ct)
    #pragma unroll
    for (int i = 0; i < 4; ++i)
      yp[(size_t)(row0 + g * 4 + i) * 128 + ct * 16 + lr] = acc[ct][i];
}

// ---------------- sparse propagate (width 128): tout = Yk + A * tin ----------------
// one wave per node, lane = 2 features (float2)

__global__ __launch_bounds__(256) void gather_kernel(const float* __restrict__ Yk,
    const float* __restrict__ tin, const int* __restrict__ offsets,
    const int* __restrict__ csr_row, const float* __restrict__ csr_norm,
    const float* __restrict__ selfnorm, float* __restrict__ tout, int n){
  int wid = threadIdx.x >> 6, lane = threadIdx.x & 63;
  int node = blockIdx.x * 4 + wid;
  if (node >= n) return;
  const float2* tin2 = (const float2*)tin;
  int e0 = offsets[node], e1 = offsets[node + 1];
  float sn = selfnorm[node];
  float2 t0 = tin2[(size_t)node * 64 + lane];
  float2 yk = ((const float2*)Yk)[(size_t)node * 64 + lane];
  float ax = yk.x + sn * t0.x;
  float ay = yk.y + sn * t0.y;
  int i = e0;
  for (; i + 4 <= e1; i += 4){
    int r0 = csr_row[i], r1 = csr_row[i+1], r2 = csr_row[i+2], r3 = csr_row[i+3];
    float w0 = csr_norm[i], w1 = csr_norm[i+1], w2 = csr_norm[i+2], w3 = csr_norm[i+3];
    float2 v0 = tin2[(size_t)r0 * 64 + lane];
    float2 v1 = tin2[(size_t)r1 * 64 + lane];
    float2 v2 = tin2[(size_t)r2 * 64 + lane];
    float2 v3 = tin2[(size_t)r3 * 64 + lane];
    ax += w0 * v0.x; ay += w0 * v0.y;
    ax += w1 * v1.x; ay += w1 * v1.y;
    ax += w2 * v2.x; ay += w2 * v2.y;
    ax += w3 * v3.x; ay += w3 * v3.y;
  }
  for (; i < e1; ++i){
    float2 v = tin2[(size_t)csr_row[i] * 64 + lane];
    float w = csr_norm[i];
    ax += w * v.x; ay += w * v.y;
  }
  float2 r; r.x = ax; r.y = ay;
  ((float2*)tout)[(size_t)node * 64 + lane] = r;
}

// ---------------- relu + split + LDS-transpose bf16 pack ----------------
// block: 64 nodes x 128 feats. emb (cols 0:64) -> out, emb_a (64:128).
// embBT [128][n] bf16 written with coalesced 64B row chunks.

__global__ __launch_bounds__(256) void relu_trans_kernel(const float* __restrict__ u,
    float* __restrict__ emb, float* __restrict__ emb_a, short* __restrict__ embBT, int n){
  __shared__ short lds[128 * 72];   // [f][node], stride 72 shorts (144B, 16B-aligned)
  int t = threadIdx.x;
  int node0 = blockIdx.x * 64;
  int nl = t >> 2;
  int f0 = (t & 3) * 32;
  int node = node0 + nl;
  if (node < n){
    const f32x4* up = (const f32x4*)(u + (size_t)node * 128 + f0);
    float* dst = (f0 < 64) ? (emb + (size_t)node * 64 + f0)
                           : (emb_a + (size_t)node * 64 + (f0 - 64));
    #pragma unroll
    for (int j4 = 0; j4 < 8; ++j4){
      f32x4 v = up[j4];
      #pragma unroll
      for (int e = 0; e < 4; ++e){
        float x = v[e] > 0.0f ? v[e] : 0.0f;
        v[e] = x;
        lds[(f0 + j4 * 4 + e) * 72 + nl] = f2bf(x);
      }
      ((f32x4*)dst)[j4] = v;
    }
  }
  __syncthreads();
  int f = t >> 1, c0 = (t & 1) * 32;
  short* op = embBT + (size_t)f * n + node0 + c0;
  const short* lp = lds + f * 72 + c0;
  if (node0 + 64 <= n){
    #pragma unroll
    for (int j = 0; j < 4; ++j)
      *(s16x8*)(op + j * 8) = *(const s16x8*)(lp + j * 8);
  } else {
    for (int j = 0; j < 32; ++j)
      if (node0 + c0 + j < n) op[j] = lp[j];
  }
}

// ---------------- readout GEMM: vsum[ks][n][128] partial = mask @ embBT^T ----------------
// 4 waves/block, each wave: 16 rows x 128 cols. Ping-pong software pipeline:
// all 10 loads of an iteration issued as a batch while MFMAs consume the other set.

__global__ __launch_bounds__(256, 4) void readout_kernel(const float* __restrict__ mask,
    const short* __restrict__ embBT, float* __restrict__ vsum, int n){
  int t = threadIdx.x;
  int w = t >> 6, l = t & 63, lr = l & 15, g = l >> 4;
  int ntile = n >> 4;
  int tile = blockIdx.x * 4 + w;
  if (tile >= ntile) tile = ntile - 1;   // duplicate last tile: benign identical writes
  int row0 = tile << 4;
  int ks = blockIdx.y;
  int kbeg = ks * 1248;
  int kend = (ks == KSPLIT - 1) ? n : kbeg + 1248;
  int klen = kend - kbeg;
  int nfull = klen >> 5;    // 39 for all splits at n=10000
  int rem = klen & 31;      // 16 on last split

  const f32x4* ap = (const f32x4*)(mask + (size_t)(row0 + lr) * n + kbeg + g * 8);
  const short* bp = embBT + (size_t)lr * n + kbeg + g * 8;
  const size_t cs = (size_t)n * 16;   // col-tile stride (shorts)

  f32x4 acc[8];
  #pragma unroll
  for (int ct = 0; ct < 8; ++ct) acc[ct] = (f32x4){0,0,0,0};

  f32x4 a0, a1, c0, c1;
  s16x8 b[8], d[8];

  a0 = ap[0]; a1 = ap[1];
  #pragma unroll
  for (int ct = 0; ct < 8; ++ct) b[ct] = *(const s16x8*)(bp + ct * cs);

  int it = 0;
  for (; it + 2 <= nfull; it += 2){
    // batch-issue loads for it+1 into (c,d)
    c0 = ap[(it + 1) * 8]; c1 = ap[(it + 1) * 8 + 1];
    #pragma unroll
    for (int ct = 0; ct < 8; ++ct) d[ct] = *(const s16x8*)(bp + ct * cs + (size_t)(it + 1) * 32);
    {
      FragU af;
      af.u[0] = pack_trunc(a0[0], a0[1]); af.u[1] = pack_trunc(a0[2], a0[3]);
      af.u[2] = pack_trunc(a1[0], a1[1]); af.u[3] = pack_trunc(a1[2], a1[3]);
      #pragma unroll
      for (int ct = 0; ct < 8; ++ct)
        acc[ct] = __builtin_amdgcn_mfma_f32_16x16x32_bf16(af.s, b[ct], acc[ct], 0, 0, 0);
    }
    // batch-issue loads for it+2 into (a,b) (clamped reload on last pair)
    int i2 = (it + 2 < nfull) ? it + 2 : nfull - 1;
    a0 = ap[i2 * 8]; a1 = ap[i2 * 8 + 1];
    #pragma unroll
    for (int ct = 0; ct < 8; ++ct) b[ct] = *(const s16x8*)(bp + ct * cs + (size_t)i2 * 32);
    {
      FragU af;
      af.u[0] = pack_trunc(c0[0], c0[1]); af.u[1] = pack_trunc(c0[2], c0[3]);
      af.u[2] = pack_trunc(c1[0], c1[1]); af.u[3] = pack_trunc(c1[2], c1[3]);
      #pragma unroll
      for (int ct = 0; ct < 8; ++ct)
        acc[ct] = __builtin_amdgcn_mfma_f32_16x16x32_bf16(af.s, d[ct], acc[ct], 0, 0, 0);
    }
  }
  if (it < nfull){   // odd trip count: last iteration sits in (a,b)
    FragU af;
    af.u[0] = pack_trunc(a0[0], a0[1]); af.u[1] = pack_trunc(a0[2], a0[3]);
    af.u[2] = pack_trunc(a1[0], a1[1]); af.u[3] = pack_trunc(a1[2], a1[3]);
    #pragma unroll
    for (int ct = 0; ct < 8; ++ct)
      acc[ct] = __builtin_amdgcn_mfma_f32_16x16x32_bf16(af.s, b[ct], acc[ct], 0, 0, 0);
  }
  if (rem){   // K tail of 16 (g<2 lanes carry data)
    FragU af; af.u = (u32x4){0,0,0,0};
    s16x8 bz = {0,0,0,0,0,0,0,0};
    s16x8 br[8];
    #pragma unroll
    for (int ct = 0; ct < 8; ++ct) br[ct] = bz;
    if (g * 8 < rem){
      f32x4 r0 = ap[nfull * 8], r1 = ap[nfull * 8 + 1];
      af.u[0] = pack_trunc(r0[0], r0[1]); af.u[1] = pack_trunc(r0[2], r0[3]);
      af.u[2] = pack_trunc(r1[0], r1[1]); af.u[3] = pack_trunc(r1[2], r1[3]);
      #pragma unroll
      for (int ct = 0; ct < 8; ++ct) br[ct] = *(const s16x8*)(bp + ct * cs + (size_t)nfull * 32);
    }
    #pragma unroll
    for (int ct = 0; ct < 8; ++ct)
      acc[ct] = __builtin_amdgcn_mfma_f32_16x16x32_bf16(af.s, br[ct], acc[ct], 0, 0, 0);
  }

  float* vs = vsum + (size_t)ks * n * 128;
  #pragma unroll
  for (int ct = 0; ct < 8; ++ct)
    #pragma unroll
    for (int i = 0; i < 4; ++i)
      vs[(size_t)(row0 + g * 4 + i) * 128 + ct * 16 + lr] = acc[ct][i];
}

// ---------------- g = sigmoid(v / ||v||), summing K-split partials ----------------

__global__ __launch_bounds__(256) void gnorm_kernel(const float* __restrict__ vsum,
                                                    float* __restrict__ gbuf, int n){
  int wid = threadIdx.x >> 6, lane = threadIdx.x & 63;
  int node = blockIdx.x * 4 + wid;
  if (node >= n) return;
  size_t stride = (size_t)n * 128;
  float v1 = 0.0f, v2 = 0.0f;
  #pragma unroll
  for (int ks = 0; ks < KSPLIT; ++ks){
    v1 += vsum[ks * stride + (size_t)node * 128 + lane];
    v2 += vsum[ks * stride + (size_t)node * 128 + 64 + lane];
  }
  float s1 = v1 * v1, s2 = v2 * v2;
  for (int off = 32; off >= 1; off >>= 1){
    s1 += __shfl_xor(s1, off);
    s2 += __shfl_xor(s2, off);
  }
  float i1 = v1 / fmaxf(sqrtf(s1), 1e-12f);
  float i2 = v2 / fmaxf(sqrtf(s2), 1e-12f);
  gbuf[(size_t)node * 128 + lane]      = 1.0f / (1.0f + expf(-i1));
  gbuf[(size_t)node * 128 + 64 + lane] = 1.0f / (1.0f + expf(-i2));
}

// ---------------- bilinear discriminator ----------------

__global__ __launch_bounds__(256) void disc_kernel(const float* __restrict__ emb,
    const float* __restrict__ emb_a, const float* __restrict__ gbuf,
    const float* __restrict__ Wb, const float* __restrict__ bptr,
    float* __restrict__ ret, float* __restrict__ reta, int n){
  __shared__ float Wl[64][65];
  int t = threadIdx.x;
  for (int i = t; i < 4096; i += 256) Wl[i >> 6][i & 63] = Wb[i];
  __syncthreads();
  int wid = t >> 6, lane = t & 63;
  int node = blockIdx.x * 4 + wid;
  if (node >= n) return;
  float e1 = emb[(size_t)node * 64 + lane];
  float e2 = emb_a[(size_t)node * 64 + lane];
  float g1 = gbuf[(size_t)node * 128 + lane];
  float g2 = gbuf[(size_t)node * 128 + 64 + lane];
  float u1 = 0.0f, u2 = 0.0f;
  for (int e = 0; e < 64; ++e){
    float wv = Wl[lane][e];
    u1 += wv * __shfl(g1, e);
    u2 += wv * __shfl(g2, e);
  }
  float p1 = e1 * u1, p2 = e2 * u1, p3 = e2 * u2, p4 = e1 * u2;
  for (int off = 32; off >= 1; off >>= 1){
    p1 += __shfl_xor(p1, off); p2 += __shfl_xor(p2, off);
    p3 += __shfl_xor(p3, off); p4 += __shfl_xor(p4, off);
  }
  if (lane == 0){
    float b = bptr[0];
    ret[(size_t)node * 2 + 0]  = p1 + b;
    ret[(size_t)node * 2 + 1]  = p2 + b;
    reta[(size_t)node * 2 + 0] = p3 + b;
    reta[(size_t)node * 2 + 1] = p4 + b;
  }
}

// ---------------- launch ----------------

extern "C" void kernel_launch(void* const* d_in, const int* in_sizes, int n_in,
                              void* d_out, int out_size, void* d_ws, size_t ws_size,
                              hipStream_t stream) {
  const float* feat   = (const float*)d_in[0];
  const float* feat_a = (const float*)d_in[1];
  const int*   ei     = (const int*)d_in[2];
  const float* mask   = (const float*)d_in[3];
  const float* W      = (const float*)d_in[4];
  const float* Wb     = (const float*)d_in[5];
  const float* bsc    = (const float*)d_in[6];
  const int n = in_sizes[0] / F_IN;      // 10000
  const int E = in_sizes[2] / 2;         // 640000
  const size_t sl128 = (size_t)n * 128;  // merged slab elements

  float* out  = (float*)d_out;
  float* ret  = out + (size_t)n * F_OUT;
  float* reta = ret + (size_t)n * 2;

  char* wsb = (char*)d_ws;
  size_t off = 0;
  #define WSALLOC(ptr, T, cnt) T* ptr = (T*)(wsb + off); off = (off + sizeof(T)*(size_t)(cnt) + 255) & ~(size_t)255
  WSALLOC(deg, int, n);
  WSALLOC(counts, int, n);
  WSALLOC(offs, int, n + 1);
  WSALLOC(cursors, int, n);
  WSALLOC(dis, float, n);
  WSALLOC(selfnorm, float, n);
  WSALLOC(csr_row, int, E);
  WSALLOC(csr_norm, float, E);
  WSALLOC(WT, short, 5 * 64 * 256);
  WSALLOC(Yc, float, sl128 * 5);
  WSALLOC(u0, float, sl128);
  WSALLOC(u1, float, sl128);
  WSALLOC(emb_a, float, (size_t)n * F_OUT);
  WSALLOC(embBT, short, (size_t)128 * n);
  WSALLOC(vsum, float, sl128 * KSPLIT);
  WSALLOC(gbuf, float, sl128);
  (void)ws_size; (void)n_in; (void)out_size;

  hipMemsetAsync(deg, 0, (size_t)n * 4, stream);
  hipMemsetAsync(counts, 0, (size_t)n * 4, stream);

  int eb = (E + 255) / 256;
  hist_kernel<<<eb, 256, 0, stream>>>(ei, E, deg, counts);
  dis_kernel<<<(n + 255) / 256, 256, 0, stream>>>(deg, dis, selfnorm, n);
  scan_kernel<<<1, 1024, 0, stream>>>(counts, offs, cursors, n);
  fill_kernel<<<eb, 256, 0, stream>>>(ei, E, dis, cursors, csr_row, csr_norm);

  wt_kernel<<<(5 * 64 * 256 + 255) / 256, 256, 0, stream>>>(W, WT);
  fgemm_kernel<<<dim3(n / 16, 5, 2), 64, 0, stream>>>(feat, feat_a, WT, Yc, n);

  int gb = (n + 3) / 4;
  // Horner: u = Yc4; u = Yc3 + A u; ... ; u = Yc0 + A u
  gather_kernel<<<gb, 256, 0, stream>>>(Yc + 3 * sl128, Yc + 4 * sl128, offs, csr_row, csr_norm, selfnorm, u0, n);
  gather_kernel<<<gb, 256, 0, stream>>>(Yc + 2 * sl128, u0, offs, csr_row, csr_norm, selfnorm, u1, n);
  gather_kernel<<<gb, 256, 0, stream>>>(Yc + 1 * sl128, u1, offs, csr_row, csr_norm, selfnorm, u0, n);
  gather_kernel<<<gb, 256, 0, stream>>>(Yc + 0 * sl128, u0, offs, csr_row, csr_norm, selfnorm, u1, n);
  relu_trans_kernel<<<(n + 63) / 64, 256, 0, stream>>>(u1, out, emb_a, embBT, n);

  readout_kernel<<<dim3((n / 16 + 3) / 4, KSPLIT), 256, 0, stream>>>(mask, embBT, vsum, n);
  gnorm_kernel<<<gb, 256, 0, stream>>>(vsum, gbuf, n);
  disc_kernel<<<gb, 256, 0, stream>>>(out, emb_a, gbuf, Wb, bsc, ret, reta, n);
}

// Round 4
// 502.655 us; speedup vs baseline: 1.4612x; 1.1505x over previous
//
#include <hip/hip_runtime.h>
#include <hip/hip_bf16.h>

typedef float f32x4 __attribute__((ext_vector_type(4)));
typedef short s16x8 __attribute__((ext_vector_type(8)));
typedef unsigned int u32x4 __attribute__((ext_vector_type(4)));

#define F_IN 256
#define F_OUT 64
#define KSPLIT 8

static __device__ __forceinline__ short f2bf(float f){  // RTNE
  union { float f; unsigned u; } x; x.f = f;
  unsigned r = (x.u + 0x7FFFu + ((x.u >> 16) & 1u)) >> 16;
  return (short)r;
}

static __device__ __forceinline__ unsigned pack_rtne(float f0, float f1){
  return ((unsigned)(unsigned short)f2bf(f0)) | ((unsigned)(unsigned short)f2bf(f1) << 16);
}

// truncation pack (bias cancels in L2-normalize downstream of the mask GEMM)
static __device__ __forceinline__ unsigned pack_trunc(float f0, float f1){
  return (__float_as_uint(f0) >> 16) | (__float_as_uint(f1) & 0xFFFF0000u);
}

union FragU { u32x4 u; s16x8 s; };

// ---------------- degree / CSR build ----------------

__global__ void hist_kernel(const int* __restrict__ ei, int E, int* __restrict__ deg,
                            int* __restrict__ counts){
  int e = blockIdx.x * blockDim.x + threadIdx.x;
  if (e >= E) return;
  int r = ei[e], c = ei[E + e];
  if (r != c) atomicAdd(&deg[r], 1);
  atomicAdd(&counts[c], 1);
}

__global__ void dis_kernel(const int* __restrict__ deg, float* __restrict__ dis,
                           float* __restrict__ selfnorm, int n){
  int i = blockIdx.x * blockDim.x + threadIdx.x;
  if (i >= n) return;
  float d = (float)(deg[i] + 1);   // +1: appended self-loop
  dis[i] = rsqrtf(d);
  selfnorm[i] = 1.0f / d;
}

__global__ __launch_bounds__(1024) void scan_kernel(const int* __restrict__ counts,
                                                    int* __restrict__ offsets,
                                                    int* __restrict__ cursors, int n){
  const int C = 10;
  __shared__ int lds[1024];
  int tid = threadIdx.x;
  int base = tid * C;
  int s = 0;
  for (int i = 0; i < C; ++i){ int idx = base + i; if (idx < n) s += counts[idx]; }
  lds[tid] = s; __syncthreads();
  for (int off = 1; off < 1024; off <<= 1){
    int add = (tid >= off) ? lds[tid - off] : 0;
    __syncthreads();
    lds[tid] += add;
    __syncthreads();
  }
  int run = lds[tid] - s;
  for (int i = 0; i < C; ++i){
    int idx = base + i;
    if (idx < n){ offsets[idx] = run; cursors[idx] = run; run += counts[idx]; }
  }
  if (tid == 1023) offsets[n] = lds[1023];
}

__global__ void fill_kernel(const int* __restrict__ ei, int E, const float* __restrict__ dis,
                            int* __restrict__ cursors, int* __restrict__ csr_row,
                            float* __restrict__ csr_norm){
  int e = blockIdx.x * blockDim.x + threadIdx.x;
  if (e >= E) return;
  int r = ei[e], c = ei[E + e];
  int pos = atomicAdd(&cursors[c], 1);
  csr_row[pos] = r;
  csr_norm[pos] = (r == c) ? 0.0f : dis[r] * dis[c];
}

// W [1280,64] f32 -> WT [5][64][256] bf16 (transposed per slab)
__global__ void wt_kernel(const float* __restrict__ W, short* __restrict__ WT){
  int idx = blockIdx.x * blockDim.x + threadIdx.x;
  if (idx >= 5 * 64 * 256) return;
  int k = idx & 255, c = (idx >> 8) & 63, by = idx >> 14;
  WT[idx] = f2bf(W[(size_t)(by * 256 + k) * 64 + c]);
}

// ---------------- feature GEMM (bf16 MFMA, fused f32->bf16 cast) ----------------
// Yc[by][M][128]: cols [0:64) = feat slab, [64:128) = feat_a slab.
// grid (M/16, 5, 2), 64 threads.

__global__ __launch_bounds__(64) void fgemm_kernel(const float* __restrict__ X0,
                                                   const float* __restrict__ X1,
                                                   const short* __restrict__ WT,
                                                   float* __restrict__ Yc, int M){
  const float* X = blockIdx.z ? X1 : X0;
  int l = threadIdx.x, lr = l & 15, g = l >> 4;
  int row0 = blockIdx.x * 16, by = blockIdx.y;
  const f32x4* ap = (const f32x4*)(X + (size_t)(row0 + lr) * F_IN + g * 8);
  const s16x8* bp[4];
  #pragma unroll
  for (int ct = 0; ct < 4; ++ct)
    bp[ct] = (const s16x8*)(WT + ((size_t)by * 64 + ct * 16 + lr) * F_IN + g * 8);
  f32x4 acc[4];
  #pragma unroll
  for (int ct = 0; ct < 4; ++ct) acc[ct] = (f32x4){0,0,0,0};
  #pragma unroll
  for (int it = 0; it < 8; ++it){
    f32x4 x0 = ap[it * 8], x1 = ap[it * 8 + 1];
    FragU af;
    af.u[0] = pack_rtne(x0[0], x0[1]);
    af.u[1] = pack_rtne(x0[2], x0[3]);
    af.u[2] = pack_rtne(x1[0], x1[1]);
    af.u[3] = pack_rtne(x1[2], x1[3]);
    #pragma unroll
    for (int ct = 0; ct < 4; ++ct)
      acc[ct] = __builtin_amdgcn_mfma_f32_16x16x32_bf16(af.s, bp[ct][it * 4], acc[ct], 0, 0, 0);
  }
  float* yp = Yc + (size_t)by * M * 128 + blockIdx.z * 64;
  #pragma unroll
  for (int ct = 0; ct < 4; ++ct)
    #pragma unroll
    for (int i = 0; i < 4; ++i)
      yp[(size_t)(row0 + g * 4 + i) * 128 + ct * 16 + lr] = acc[ct][i];
}

// ---------------- sparse propagate (width 128): tout = Yk + A * tin ----------------

__global__ __launch_bounds__(256) void gather_kernel(const float* __restrict__ Yk,
    const float* __restrict__ tin, const int* __restrict__ offsets,
    const int* __restrict__ csr_row, const float* __restrict__ csr_norm,
    const float* __restrict__ selfnorm, float* __restrict__ tout, int n){
  int wid = threadIdx.x >> 6, lane = threadIdx.x & 63;
  int node = blockIdx.x * 4 + wid;
  if (node >= n) return;
  const float2* tin2 = (const float2*)tin;
  int e0 = offsets[node], e1 = offsets[node + 1];
  float sn = selfnorm[node];
  float2 t0 = tin2[(size_t)node * 64 + lane];
  float2 yk = ((const float2*)Yk)[(size_t)node * 64 + lane];
  float ax = yk.x + sn * t0.x;
  float ay = yk.y + sn * t0.y;
  int i = e0;
  for (; i + 4 <= e1; i += 4){
    int r0 = csr_row[i], r1 = csr_row[i+1], r2 = csr_row[i+2], r3 = csr_row[i+3];
    float w0 = csr_norm[i], w1 = csr_norm[i+1], w2 = csr_norm[i+2], w3 = csr_norm[i+3];
    float2 v0 = tin2[(size_t)r0 * 64 + lane];
    float2 v1 = tin2[(size_t)r1 * 64 + lane];
    float2 v2 = tin2[(size_t)r2 * 64 + lane];
    float2 v3 = tin2[(size_t)r3 * 64 + lane];
    ax += w0 * v0.x; ay += w0 * v0.y;
    ax += w1 * v1.x; ay += w1 * v1.y;
    ax += w2 * v2.x; ay += w2 * v2.y;
    ax += w3 * v3.x; ay += w3 * v3.y;
  }
  for (; i < e1; ++i){
    float2 v = tin2[(size_t)csr_row[i] * 64 + lane];
    float w = csr_norm[i];
    ax += w * v.x; ay += w * v.y;
  }
  float2 r; r.x = ax; r.y = ay;
  ((float2*)tout)[(size_t)node * 64 + lane] = r;
}

// ---------------- relu + split + LDS-transpose bf16 pack ----------------

__global__ __launch_bounds__(256) void relu_trans_kernel(const float* __restrict__ u,
    float* __restrict__ emb, float* __restrict__ emb_a, short* __restrict__ embBT, int n){
  __shared__ short lds[128 * 72];
  int t = threadIdx.x;
  int node0 = blockIdx.x * 64;
  int nl = t >> 2;
  int f0 = (t & 3) * 32;
  int node = node0 + nl;
  if (node < n){
    const f32x4* up = (const f32x4*)(u + (size_t)node * 128 + f0);
    float* dst = (f0 < 64) ? (emb + (size_t)node * 64 + f0)
                           : (emb_a + (size_t)node * 64 + (f0 - 64));
    #pragma unroll
    for (int j4 = 0; j4 < 8; ++j4){
      f32x4 v = up[j4];
      #pragma unroll
      for (int e = 0; e < 4; ++e){
        float x = v[e] > 0.0f ? v[e] : 0.0f;
        v[e] = x;
        lds[(f0 + j4 * 4 + e) * 72 + nl] = f2bf(x);
      }
      ((f32x4*)dst)[j4] = v;
    }
  }
  __syncthreads();
  int f = t >> 1, c0 = (t & 1) * 32;
  short* op = embBT + (size_t)f * n + node0 + c0;
  const short* lp = lds + f * 72 + c0;
  if (node0 + 64 <= n){
    #pragma unroll
    for (int j = 0; j < 4; ++j)
      *(s16x8*)(op + j * 8) = *(const s16x8*)(lp + j * 8);
  } else {
    for (int j = 0; j < 32; ++j)
      if (node0 + c0 + j < n) op[j] = lp[j];
  }
}

// ---------------- readout GEMM: vsum[ks][n][128] partial = mask @ embBT^T ----------------
// LDS double-buffered tile GEMM: 256 thr / 4 waves, tile 64 rows x 128 cols x BK=32.
// A (mask f32) reg-staged -> trunc-pack bf16 -> ds_write_b128; B (embBT bf16) likewise.
// 64B LDS rows: full-wave b128 accesses hit the 8-lanes/slot bandwidth floor (no swizzle).

__global__ __launch_bounds__(256, 4) void readout_kernel(const float* __restrict__ mask,
    const short* __restrict__ embBT, float* __restrict__ vsum, int n){
  __shared__ short Ab[2][64][32];
  __shared__ short Bb[2][128][32];
  int t = threadIdx.x;
  int w = t >> 6, l = t & 63, lr = l & 15, g = l >> 4;
  int row0 = blockIdx.x * 64;
  int ks = blockIdx.y;

  int steps_total = (n + 31) >> 5;               // 313
  int per = steps_total / KSPLIT, rem = steps_total % KSPLIT;
  int sbeg = ks * per + (ks < rem ? ks : rem);
  int scnt = per + (ks < rem ? 1 : 0);
  int kb0 = sbeg << 5;

  // staging assignment
  int ar = t >> 2, akc = (t & 3) << 3;           // A: row(0..63), k-chunk of 8 f32
  int bc = t >> 1, bkc = (t & 1) << 4;           // B: col(0..127), k-chunk of 16 sh
  bool arow_ok = (row0 + ar) < n;
  const float* aptr = mask + (size_t)(row0 + ar) * n;
  const short* bptr = embBT + (size_t)bc * n;

  f32x4 a0, a1; s16x8 b0, b1;
  const s16x8 bz = {0,0,0,0,0,0,0,0};

  #define LOADAB(kb) do{ \
    a0 = (f32x4){0,0,0,0}; a1 = a0; \
    if (arow_ok && (kb) + akc < n){ \
      const f32x4* p_ = (const f32x4*)(aptr + (kb) + akc); \
      a0 = p_[0]; a1 = p_[1]; \
    } \
    b0 = bz; b1 = bz; \
    if ((kb) + bkc < n)     b0 = *(const s16x8*)(bptr + (kb) + bkc); \
    if ((kb) + bkc + 8 < n) b1 = *(const s16x8*)(bptr + (kb) + bkc + 8); \
  }while(0)

  #define STORELDS(bi) do{ \
    u32x4 ap_; \
    ap_[0] = pack_trunc(a0[0], a0[1]); ap_[1] = pack_trunc(a0[2], a0[3]); \
    ap_[2] = pack_trunc(a1[0], a1[1]); ap_[3] = pack_trunc(a1[2], a1[3]); \
    *(u32x4*)&Ab[bi][ar][akc] = ap_; \
    *(s16x8*)&Bb[bi][bc][bkc] = b0; \
    *(s16x8*)&Bb[bi][bc][bkc + 8] = b1; \
  }while(0)

  f32x4 acc[8];
  #pragma unroll
  for (int ct = 0; ct < 8; ++ct) acc[ct] = (f32x4){0,0,0,0};

  LOADAB(kb0);
  STORELDS(0);
  __syncthreads();

  int cur = 0;
  for (int s = 0; s < scnt; ++s){
    bool have_next = (s + 1) < scnt;
    if (have_next){ int kbn = kb0 + (s + 1) * 32; LOADAB(kbn); }
    // compute from buf[cur]
    {
      s16x8 af = *(const s16x8*)&Ab[cur][(w << 4) + lr][g * 8];
      #pragma unroll
      for (int ct = 0; ct < 8; ++ct){
        s16x8 bf = *(const s16x8*)&Bb[cur][ct * 16 + lr][g * 8];
        acc[ct] = __builtin_amdgcn_mfma_f32_16x16x32_bf16(af, bf, acc[ct], 0, 0, 0);
      }
    }
    __syncthreads();
    if (have_next) STORELDS(cur ^ 1);
    __syncthreads();
    cur ^= 1;
  }
  #undef LOADAB
  #undef STORELDS

  float* vs = vsum + (size_t)ks * n * 128;
  int rbase = row0 + (w << 4);
  #pragma unroll
  for (int ct = 0; ct < 8; ++ct)
    #pragma unroll
    for (int i = 0; i < 4; ++i){
      int gr = rbase + g * 4 + i;
      if (gr < n) vs[(size_t)gr * 128 + ct * 16 + lr] = acc[ct][i];
    }
}

// ---------------- g = sigmoid(v / ||v||), summing K-split partials ----------------

__global__ __launch_bounds__(256) void gnorm_kernel(const float* __restrict__ vsum,
                                                    float* __restrict__ gbuf, int n){
  int wid = threadIdx.x >> 6, lane = threadIdx.x & 63;
  int node = blockIdx.x * 4 + wid;
  if (node >= n) return;
  size_t stride = (size_t)n * 128;
  float v1 = 0.0f, v2 = 0.0f;
  #pragma unroll
  for (int ks = 0; ks < KSPLIT; ++ks){
    v1 += vsum[ks * stride + (size_t)node * 128 + lane];
    v2 += vsum[ks * stride + (size_t)node * 128 + 64 + lane];
  }
  float s1 = v1 * v1, s2 = v2 * v2;
  for (int off = 32; off >= 1; off >>= 1){
    s1 += __shfl_xor(s1, off);
    s2 += __shfl_xor(s2, off);
  }
  float i1 = v1 / fmaxf(sqrtf(s1), 1e-12f);
  float i2 = v2 / fmaxf(sqrtf(s2), 1e-12f);
  gbuf[(size_t)node * 128 + lane]      = 1.0f / (1.0f + expf(-i1));
  gbuf[(size_t)node * 128 + 64 + lane] = 1.0f / (1.0f + expf(-i2));
}

// ---------------- bilinear discriminator ----------------

__global__ __launch_bounds__(256) void disc_kernel(const float* __restrict__ emb,
    const float* __restrict__ emb_a, const float* __restrict__ gbuf,
    const float* __restrict__ Wb, const float* __restrict__ bptr,
    float* __restrict__ ret, float* __restrict__ reta, int n){
  __shared__ float Wl[64][65];
  int t = threadIdx.x;
  for (int i = t; i < 4096; i += 256) Wl[i >> 6][i & 63] = Wb[i];
  __syncthreads();
  int wid = t >> 6, lane = t & 63;
  int node = blockIdx.x * 4 + wid;
  if (node >= n) return;
  float e1 = emb[(size_t)node * 64 + lane];
  float e2 = emb_a[(size_t)node * 64 + lane];
  float g1 = gbuf[(size_t)node * 128 + lane];
  float g2 = gbuf[(size_t)node * 128 + 64 + lane];
  float u1 = 0.0f, u2 = 0.0f;
  for (int e = 0; e < 64; ++e){
    float wv = Wl[lane][e];
    u1 += wv * __shfl(g1, e);
    u2 += wv * __shfl(g2, e);
  }
  float p1 = e1 * u1, p2 = e2 * u1, p3 = e2 * u2, p4 = e1 * u2;
  for (int off = 32; off >= 1; off >>= 1){
    p1 += __shfl_xor(p1, off); p2 += __shfl_xor(p2, off);
    p3 += __shfl_xor(p3, off); p4 += __shfl_xor(p4, off);
  }
  if (lane == 0){
    float b = bptr[0];
    ret[(size_t)node * 2 + 0]  = p1 + b;
    ret[(size_t)node * 2 + 1]  = p2 + b;
    reta[(size_t)node * 2 + 0] = p3 + b;
    reta[(size_t)node * 2 + 1] = p4 + b;
  }
}

// ---------------- launch ----------------

extern "C" void kernel_launch(void* const* d_in, const int* in_sizes, int n_in,
                              void* d_out, int out_size, void* d_ws, size_t ws_size,
                              hipStream_t stream) {
  const float* feat   = (const float*)d_in[0];
  const float* feat_a = (const float*)d_in[1];
  const int*   ei     = (const int*)d_in[2];
  const float* mask   = (const float*)d_in[3];
  const float* W      = (const float*)d_in[4];
  const float* Wb     = (const float*)d_in[5];
  const float* bsc    = (const float*)d_in[6];
  const int n = in_sizes[0] / F_IN;      // 10000
  const int E = in_sizes[2] / 2;         // 640000
  const size_t sl128 = (size_t)n * 128;

  float* out  = (float*)d_out;
  float* ret  = out + (size_t)n * F_OUT;
  float* reta = ret + (size_t)n * 2;

  char* wsb = (char*)d_ws;
  size_t off = 0;
  #define WSALLOC(ptr, T, cnt) T* ptr = (T*)(wsb + off); off = (off + sizeof(T)*(size_t)(cnt) + 255) & ~(size_t)255
  WSALLOC(deg, int, n);
  WSALLOC(counts, int, n);
  WSALLOC(offs, int, n + 1);
  WSALLOC(cursors, int, n);
  WSALLOC(dis, float, n);
  WSALLOC(selfnorm, float, n);
  WSALLOC(csr_row, int, E);
  WSALLOC(csr_norm, float, E);
  WSALLOC(WT, short, 5 * 64 * 256);
  WSALLOC(Yc, float, sl128 * 5);
  WSALLOC(u0, float, sl128);
  WSALLOC(u1, float, sl128);
  WSALLOC(emb_a, float, (size_t)n * F_OUT);
  WSALLOC(embBT, short, (size_t)128 * n);
  WSALLOC(vsum, float, sl128 * KSPLIT);
  WSALLOC(gbuf, float, sl128);
  (void)ws_size; (void)n_in; (void)out_size;

  hipMemsetAsync(deg, 0, (size_t)n * 4, stream);
  hipMemsetAsync(counts, 0, (size_t)n * 4, stream);

  int eb = (E + 255) / 256;
  hist_kernel<<<eb, 256, 0, stream>>>(ei, E, deg, counts);
  dis_kernel<<<(n + 255) / 256, 256, 0, stream>>>(deg, dis, selfnorm, n);
  scan_kernel<<<1, 1024, 0, stream>>>(counts, offs, cursors, n);
  fill_kernel<<<eb, 256, 0, stream>>>(ei, E, dis, cursors, csr_row, csr_norm);

  wt_kernel<<<(5 * 64 * 256 + 255) / 256, 256, 0, stream>>>(W, WT);
  fgemm_kernel<<<dim3(n / 16, 5, 2), 64, 0, stream>>>(feat, feat_a, WT, Yc, n);

  int gb = (n + 3) / 4;
  gather_kernel<<<gb, 256, 0, stream>>>(Yc + 3 * sl128, Yc + 4 * sl128, offs, csr_row, csr_norm, selfnorm, u0, n);
  gather_kernel<<<gb, 256, 0, stream>>>(Yc + 2 * sl128, u0, offs, csr_row, csr_norm, selfnorm, u1, n);
  gather_kernel<<<gb, 256, 0, stream>>>(Yc + 1 * sl128, u1, offs, csr_row, csr_norm, selfnorm, u0, n);
  gather_kernel<<<gb, 256, 0, stream>>>(Yc + 0 * sl128, u0, offs, csr_row, csr_norm, selfnorm, u1, n);
  relu_trans_kernel<<<(n + 63) / 64, 256, 0, stream>>>(u1, out, emb_a, embBT, n);

  readout_kernel<<<dim3((n + 63) / 64, KSPLIT), 256, 0, stream>>>(mask, embBT, vsum, n);
  gnorm_kernel<<<gb, 256, 0, stream>>>(vsum, gbuf, n);
  disc_kernel<<<gb, 256, 0, stream>>>(out, emb_a, gbuf, Wb, bsc, ret, reta, n);
}

// Round 5
// 457.006 us; speedup vs baseline: 1.6072x; 1.0999x over previous
//
#include <hip/hip_runtime.h>
#include <hip/hip_bf16.h>

typedef float f32x4 __attribute__((ext_vector_type(4)));
typedef short s16x8 __attribute__((ext_vector_type(8)));
typedef unsigned int u32x4 __attribute__((ext_vector_type(4)));

#define F_IN 256
#define F_OUT 64
#define KSPLIT 8

static __device__ __forceinline__ short f2bf(float f){  // RTNE
  union { float f; unsigned u; } x; x.f = f;
  unsigned r = (x.u + 0x7FFFu + ((x.u >> 16) & 1u)) >> 16;
  return (short)r;
}

static __device__ __forceinline__ unsigned pack_rtne(float f0, float f1){
  return ((unsigned)(unsigned short)f2bf(f0)) | ((unsigned)(unsigned short)f2bf(f1) << 16);
}

// truncation pack (bias cancels in L2-normalize downstream of the mask GEMM)
static __device__ __forceinline__ unsigned pack_trunc(float f0, float f1){
  return (__float_as_uint(f0) >> 16) | (__float_as_uint(f1) & 0xFFFF0000u);
}

static __device__ __forceinline__ float bf_lo(unsigned u){ return __uint_as_float(u << 16); }
static __device__ __forceinline__ float bf_hi(unsigned u){ return __uint_as_float(u & 0xFFFF0000u); }

union FragU { u32x4 u; s16x8 s; };

// ---------------- degree / CSR build ----------------

__global__ void hist_kernel(const int* __restrict__ ei, int E, int* __restrict__ deg,
                            int* __restrict__ counts){
  int e = blockIdx.x * blockDim.x + threadIdx.x;
  if (e >= E) return;
  int r = ei[e], c = ei[E + e];
  if (r != c) atomicAdd(&deg[r], 1);
  atomicAdd(&counts[c], 1);
}

__global__ void dis_kernel(const int* __restrict__ deg, float* __restrict__ dis,
                           float* __restrict__ selfnorm, int n){
  int i = blockIdx.x * blockDim.x + threadIdx.x;
  if (i >= n) return;
  float d = (float)(deg[i] + 1);   // +1: appended self-loop
  dis[i] = rsqrtf(d);
  selfnorm[i] = 1.0f / d;
}

__global__ __launch_bounds__(1024) void scan_kernel(const int* __restrict__ counts,
                                                    int* __restrict__ offsets,
                                                    int* __restrict__ cursors, int n){
  const int C = 10;
  __shared__ int lds[1024];
  int tid = threadIdx.x;
  int base = tid * C;
  int s = 0;
  for (int i = 0; i < C; ++i){ int idx = base + i; if (idx < n) s += counts[idx]; }
  lds[tid] = s; __syncthreads();
  for (int off = 1; off < 1024; off <<= 1){
    int add = (tid >= off) ? lds[tid - off] : 0;
    __syncthreads();
    lds[tid] += add;
    __syncthreads();
  }
  int run = lds[tid] - s;
  for (int i = 0; i < C; ++i){
    int idx = base + i;
    if (idx < n){ offsets[idx] = run; cursors[idx] = run; run += counts[idx]; }
  }
  if (tid == 1023) offsets[n] = lds[1023];
}

__global__ void fill_kernel(const int* __restrict__ ei, int E, const float* __restrict__ dis,
                            int* __restrict__ cursors, int* __restrict__ csr_row,
                            float* __restrict__ csr_norm){
  int e = blockIdx.x * blockDim.x + threadIdx.x;
  if (e >= E) return;
  int r = ei[e], c = ei[E + e];
  int pos = atomicAdd(&cursors[c], 1);
  csr_row[pos] = r;
  csr_norm[pos] = (r == c) ? 0.0f : dis[r] * dis[c];
}

// W [1280,64] f32 -> WT [5][64][256] bf16 (transposed per slab)
__global__ void wt_kernel(const float* __restrict__ W, short* __restrict__ WT){
  int idx = blockIdx.x * blockDim.x + threadIdx.x;
  if (idx >= 5 * 64 * 256) return;
  int k = idx & 255, c = (idx >> 8) & 63, by = idx >> 14;
  WT[idx] = f2bf(W[(size_t)(by * 256 + k) * 64 + c]);
}

// ---------------- feature GEMM: A-strip in regs, all 5 slabs per block ----------------
// Yc[by][M][128] f32 (z-half cols); also emits t0bf = bf16(Yc slab4). grid (M/16, 2).

__global__ __launch_bounds__(64) void fgemm_kernel(const float* __restrict__ X0,
                                                   const float* __restrict__ X1,
                                                   const short* __restrict__ WT,
                                                   float* __restrict__ Yc,
                                                   short* __restrict__ t0bf, int M){
  int bz = blockIdx.y;
  const float* X = bz ? X1 : X0;
  int l = threadIdx.x, lr = l & 15, g = l >> 4;
  int row0 = blockIdx.x * 16;
  const f32x4* ap = (const f32x4*)(X + (size_t)(row0 + lr) * F_IN + g * 8);
  s16x8 afr[8];
  #pragma unroll
  for (int it = 0; it < 8; ++it){
    f32x4 x0 = ap[it * 8], x1 = ap[it * 8 + 1];
    FragU af;
    af.u[0] = pack_rtne(x0[0], x0[1]); af.u[1] = pack_rtne(x0[2], x0[3]);
    af.u[2] = pack_rtne(x1[0], x1[1]); af.u[3] = pack_rtne(x1[2], x1[3]);
    afr[it] = af.s;
  }
  for (int by = 0; by < 5; ++by){
    f32x4 acc[4];
    #pragma unroll
    for (int ct = 0; ct < 4; ++ct) acc[ct] = (f32x4){0,0,0,0};
    const s16x8* bp[4];
    #pragma unroll
    for (int ct = 0; ct < 4; ++ct)
      bp[ct] = (const s16x8*)(WT + ((size_t)by * 64 + ct * 16 + lr) * F_IN + g * 8);
    #pragma unroll
    for (int it = 0; it < 8; ++it)
      #pragma unroll
      for (int ct = 0; ct < 4; ++ct)
        acc[ct] = __builtin_amdgcn_mfma_f32_16x16x32_bf16(afr[it], bp[ct][it * 4], acc[ct], 0, 0, 0);
    float* yp = Yc + (size_t)by * M * 128 + (size_t)bz * 64;
    #pragma unroll
    for (int ct = 0; ct < 4; ++ct)
      #pragma unroll
      for (int i = 0; i < 4; ++i){
        int grow = row0 + g * 4 + i;
        yp[(size_t)grow * 128 + ct * 16 + lr] = acc[ct][i];
        if (by == 4) t0bf[(size_t)grow * 128 + bz * 64 + ct * 16 + lr] = f2bf(acc[ct][i]);
      }
  }
}

// ---------------- sparse propagate (bf16 messages): tout = Yk + A * tin ----------------
// one wave per node, lane = 2 features packed in one u32 (2 bf16)

__global__ __launch_bounds__(256) void gather_kernel(const float* __restrict__ Yk,
    const unsigned* __restrict__ tinb, const int* __restrict__ offsets,
    const int* __restrict__ csr_row, const float* __restrict__ csr_norm,
    const float* __restrict__ selfnorm, unsigned* __restrict__ toutb,
    float* __restrict__ toutf, int n, int wantf){
  int wid = threadIdx.x >> 6, lane = threadIdx.x & 63;
  int node = blockIdx.x * 4 + wid;
  if (node >= n) return;
  int e0 = offsets[node], e1 = offsets[node + 1];
  float sn = selfnorm[node];
  unsigned t0 = tinb[(size_t)node * 64 + lane];
  float2 yk = ((const float2*)Yk)[(size_t)node * 64 + lane];
  float ax = yk.x + sn * bf_lo(t0);
  float ay = yk.y + sn * bf_hi(t0);
  int i = e0;
  for (; i + 4 <= e1; i += 4){
    int r0 = csr_row[i], r1 = csr_row[i+1], r2 = csr_row[i+2], r3 = csr_row[i+3];
    float w0 = csr_norm[i], w1 = csr_norm[i+1], w2 = csr_norm[i+2], w3 = csr_norm[i+3];
    unsigned v0 = tinb[(size_t)r0 * 64 + lane];
    unsigned v1 = tinb[(size_t)r1 * 64 + lane];
    unsigned v2 = tinb[(size_t)r2 * 64 + lane];
    unsigned v3 = tinb[(size_t)r3 * 64 + lane];
    ax += w0 * bf_lo(v0); ay += w0 * bf_hi(v0);
    ax += w1 * bf_lo(v1); ay += w1 * bf_hi(v1);
    ax += w2 * bf_lo(v2); ay += w2 * bf_hi(v2);
    ax += w3 * bf_lo(v3); ay += w3 * bf_hi(v3);
  }
  for (; i < e1; ++i){
    unsigned v = tinb[(size_t)csr_row[i] * 64 + lane];
    float w = csr_norm[i];
    ax += w * bf_lo(v); ay += w * bf_hi(v);
  }
  if (wantf){
    float2 r; r.x = ax; r.y = ay;
    ((float2*)toutf)[(size_t)node * 64 + lane] = r;
  } else {
    toutb[(size_t)node * 64 + lane] = pack_rtne(ax, ay);
  }
}

// ---------------- relu + split + LDS-transpose bf16 pack ----------------

__global__ __launch_bounds__(256) void relu_trans_kernel(const float* __restrict__ u,
    float* __restrict__ emb, float* __restrict__ emb_a, short* __restrict__ embBT, int n){
  __shared__ short lds[128 * 72];
  int t = threadIdx.x;
  int node0 = blockIdx.x * 64;
  int nl = t >> 2;
  int f0 = (t & 3) * 32;
  int node = node0 + nl;
  if (node < n){
    const f32x4* up = (const f32x4*)(u + (size_t)node * 128 + f0);
    float* dst = (f0 < 64) ? (emb + (size_t)node * 64 + f0)
                           : (emb_a + (size_t)node * 64 + (f0 - 64));
    #pragma unroll
    for (int j4 = 0; j4 < 8; ++j4){
      f32x4 v = up[j4];
      #pragma unroll
      for (int e = 0; e < 4; ++e){
        float x = v[e] > 0.0f ? v[e] : 0.0f;
        v[e] = x;
        lds[(f0 + j4 * 4 + e) * 72 + nl] = f2bf(x);
      }
      ((f32x4*)dst)[j4] = v;
    }
  }
  __syncthreads();
  int f = t >> 1, c0 = (t & 1) * 32;
  short* op = embBT + (size_t)f * n + node0 + c0;
  const short* lp = lds + f * 72 + c0;
  if (node0 + 64 <= n){
    #pragma unroll
    for (int j = 0; j < 4; ++j)
      *(s16x8*)(op + j * 8) = *(const s16x8*)(lp + j * 8);
  } else {
    for (int j = 0; j < 32; ++j)
      if (node0 + c0 + j < n) op[j] = lp[j];
  }
}

// ---------------- readout GEMM: vsum[ks][n][128] partial = mask @ embBT^T ----------------
// global_load_lds double-buffered, counted-vmcnt pipeline (T3/T4), chunk-XOR swizzle
// via pre-swizzled global source + swizzled ds_read (rule 21). Tile 64x128xBK32.

__global__ __launch_bounds__(256, 4) void readout_kernel(const float* __restrict__ mask,
    const short* __restrict__ embBT, float* __restrict__ vsum, int n){
  __shared__ float Ab[2][64][32];   // logical [row][k], chunk-swizzled physically
  __shared__ short Bb[2][128][32];
  int t = threadIdx.x;
  int w = t >> 6, l = t & 63, lr = l & 15, g = l >> 4;
  int row0 = blockIdx.x * 64;
  int ks = blockIdx.y;

  int steps_total = (n + 31) >> 5;               // 313
  int per = steps_total / KSPLIT, rem = steps_total % KSPLIT;
  int sbeg = ks * per + (ks < rem ? ks : rem);
  int scnt = per + (ks < rem ? 1 : 0);
  bool tail = ((sbeg + scnt) == steps_total) && ((n & 31) != 0);
  int nf = scnt - (tail ? 1 : 0);
  int kb0 = sbeg << 5;

  // staging sources: linear LDS dest (lane*16B), source chunk pre-XOR'd
  int arow = row0 + w * 16 + (l >> 3);
  int aswz = ((l & 7) ^ ((l >> 3) & 7)) << 2;                 // float offset
  const float* asrc0 = mask + (size_t)min(arow,     n - 1) * n + aswz;
  const float* asrc1 = mask + (size_t)min(arow + 8, n - 1) * n + aswz;
  int bcol = w * 32 + (l >> 2);
  int bswz = ((l & 3) ^ ((l >> 3) & 3)) << 3;                 // short offset
  const short* bsrc0 = embBT + (size_t)bcol * n + bswz;
  const short* bsrc1 = embBT + (size_t)(bcol + 16) * n + bswz;

  #define GLDS(gp, lp) __builtin_amdgcn_global_load_lds( \
      (const __attribute__((address_space(1))) void*)(const void*)(gp), \
      (__attribute__((address_space(3))) void*)(void*)(lp), 16, 0, 0)
  #define STAGE(kb, bi) do{ \
    GLDS(asrc0 + (kb), &Ab[bi][w * 16     ][0]); \
    GLDS(asrc1 + (kb), &Ab[bi][w * 16 +  8][0]); \
    GLDS(bsrc0 + (kb), &Bb[bi][w * 32     ][0]); \
    GLDS(bsrc1 + (kb), &Bb[bi][w * 32 + 16][0]); \
  }while(0)

  f32x4 acc[8];
  #pragma unroll
  for (int ct = 0; ct < 8; ++ct) acc[ct] = (f32x4){0,0,0,0};

  if (nf > 0) STAGE(kb0, 0);
  if (nf > 1) STAGE(kb0 + 32, 1);

  for (int s = 0; s < nf; ++s){
    if (s + 1 < nf) asm volatile("s_waitcnt vmcnt(4)" ::: "memory");
    else            asm volatile("s_waitcnt vmcnt(0)" ::: "memory");
    __builtin_amdgcn_s_barrier();
    int cur = s & 1;
    f32x4 x0 = *(const f32x4*)&Ab[cur][w * 16 + lr][((2 * g)     ^ (lr & 7)) << 2];
    f32x4 x1 = *(const f32x4*)&Ab[cur][w * 16 + lr][((2 * g + 1) ^ (lr & 7)) << 2];
    FragU af;
    af.u[0] = pack_trunc(x0[0], x0[1]); af.u[1] = pack_trunc(x0[2], x0[3]);
    af.u[2] = pack_trunc(x1[0], x1[1]); af.u[3] = pack_trunc(x1[2], x1[3]);
    #pragma unroll
    for (int ct = 0; ct < 8; ++ct){
      s16x8 bf = *(const s16x8*)&Bb[cur][ct * 16 + lr][(g ^ ((lr >> 1) & 3)) << 3];
      acc[ct] = __builtin_amdgcn_mfma_f32_16x16x32_bf16(af.s, bf, acc[ct], 0, 0, 0);
    }
    asm volatile("s_waitcnt lgkmcnt(0)" ::: "memory");
    __builtin_amdgcn_s_barrier();
    if (s + 2 < nf) STAGE(kb0 + (s + 2) * 32, cur);
  }
  #undef STAGE
  #undef GLDS

  if (tail){
    int kb = kb0 + nf * 32;
    int kleft = n - kb;                          // 16
    FragU af; af.u = (u32x4){0,0,0,0};
    const s16x8 bz = {0,0,0,0,0,0,0,0};
    s16x8 bf[8];
    #pragma unroll
    for (int ct = 0; ct < 8; ++ct) bf[ct] = bz;
    int r = row0 + w * 16 + lr;
    if (g * 8 < kleft){
      if (r < n){
        const f32x4* p = (const f32x4*)(mask + (size_t)r * n + kb + g * 8);
        f32x4 r0 = p[0], r1 = p[1];
        af.u[0] = pack_trunc(r0[0], r0[1]); af.u[1] = pack_trunc(r0[2], r0[3]);
        af.u[2] = pack_trunc(r1[0], r1[1]); af.u[3] = pack_trunc(r1[2], r1[3]);
      }
      #pragma unroll
      for (int ct = 0; ct < 8; ++ct)
        bf[ct] = *(const s16x8*)(embBT + (size_t)(ct * 16 + lr) * n + kb + g * 8);
    }
    #pragma unroll
    for (int ct = 0; ct < 8; ++ct)
      acc[ct] = __builtin_amdgcn_mfma_f32_16x16x32_bf16(af.s, bf[ct], acc[ct], 0, 0, 0);
  }

  float* vs = vsum + (size_t)ks * n * 128;
  int rbase = row0 + w * 16;
  #pragma unroll
  for (int ct = 0; ct < 8; ++ct)
    #pragma unroll
    for (int i = 0; i < 4; ++i){
      int gr = rbase + g * 4 + i;
      if (gr < n) vs[(size_t)gr * 128 + ct * 16 + lr] = acc[ct][i];
    }
}

// ---------------- g = sigmoid(v / ||v||), summing K-split partials ----------------

__global__ __launch_bounds__(256) void gnorm_kernel(const float* __restrict__ vsum,
                                                    float* __restrict__ gbuf, int n){
  int wid = threadIdx.x >> 6, lane = threadIdx.x & 63;
  int node = blockIdx.x * 4 + wid;
  if (node >= n) return;
  size_t stride = (size_t)n * 128;
  float v1 = 0.0f, v2 = 0.0f;
  #pragma unroll
  for (int ks = 0; ks < KSPLIT; ++ks){
    v1 += vsum[ks * stride + (size_t)node * 128 + lane];
    v2 += vsum[ks * stride + (size_t)node * 128 + 64 + lane];
  }
  float s1 = v1 * v1, s2 = v2 * v2;
  for (int off = 32; off >= 1; off >>= 1){
    s1 += __shfl_xor(s1, off);
    s2 += __shfl_xor(s2, off);
  }
  float i1 = v1 / fmaxf(sqrtf(s1), 1e-12f);
  float i2 = v2 / fmaxf(sqrtf(s2), 1e-12f);
  gbuf[(size_t)node * 128 + lane]      = 1.0f / (1.0f + expf(-i1));
  gbuf[(size_t)node * 128 + 64 + lane] = 1.0f / (1.0f + expf(-i2));
}

// ---------------- bilinear discriminator ----------------

__global__ __launch_bounds__(256) void disc_kernel(const float* __restrict__ emb,
    const float* __restrict__ emb_a, const float* __restrict__ gbuf,
    const float* __restrict__ Wb, const float* __restrict__ bptr,
    float* __restrict__ ret, float* __restrict__ reta, int n){
  __shared__ float Wl[64][65];
  int t = threadIdx.x;
  for (int i = t; i < 4096; i += 256) Wl[i >> 6][i & 63] = Wb[i];
  __syncthreads();
  int wid = t >> 6, lane = t & 63;
  int node = blockIdx.x * 4 + wid;
  if (node >= n) return;
  float e1 = emb[(size_t)node * 64 + lane];
  float e2 = emb_a[(size_t)node * 64 + lane];
  float g1 = gbuf[(size_t)node * 128 + lane];
  float g2 = gbuf[(size_t)node * 128 + 64 + lane];
  float u1 = 0.0f, u2 = 0.0f;
  for (int e = 0; e < 64; ++e){
    float wv = Wl[lane][e];
    u1 += wv * __shfl(g1, e);
    u2 += wv * __shfl(g2, e);
  }
  float p1 = e1 * u1, p2 = e2 * u1, p3 = e2 * u2, p4 = e1 * u2;
  for (int off = 32; off >= 1; off >>= 1){
    p1 += __shfl_xor(p1, off); p2 += __shfl_xor(p2, off);
    p3 += __shfl_xor(p3, off); p4 += __shfl_xor(p4, off);
  }
  if (lane == 0){
    float b = bptr[0];
    ret[(size_t)node * 2 + 0]  = p1 + b;
    ret[(size_t)node * 2 + 1]  = p2 + b;
    reta[(size_t)node * 2 + 0] = p3 + b;
    reta[(size_t)node * 2 + 1] = p4 + b;
  }
}

// ---------------- launch ----------------

extern "C" void kernel_launch(void* const* d_in, const int* in_sizes, int n_in,
                              void* d_out, int out_size, void* d_ws, size_t ws_size,
                              hipStream_t stream) {
  const float* feat   = (const float*)d_in[0];
  const float* feat_a = (const float*)d_in[1];
  const int*   ei     = (const int*)d_in[2];
  const float* mask   = (const float*)d_in[3];
  const float* W      = (const float*)d_in[4];
  const float* Wb     = (const float*)d_in[5];
  const float* bsc    = (const float*)d_in[6];
  const int n = in_sizes[0] / F_IN;      // 10000
  const int E = in_sizes[2] / 2;         // 640000
  const size_t sl128 = (size_t)n * 128;

  float* out  = (float*)d_out;
  float* ret  = out + (size_t)n * F_OUT;
  float* reta = ret + (size_t)n * 2;

  char* wsb = (char*)d_ws;
  size_t off = 0;
  #define WSALLOC(ptr, T, cnt) T* ptr = (T*)(wsb + off); off = (off + sizeof(T)*(size_t)(cnt) + 255) & ~(size_t)255
  WSALLOC(deg, int, n);
  WSALLOC(counts, int, n);
  WSALLOC(offs, int, n + 1);
  WSALLOC(cursors, int, n);
  WSALLOC(dis, float, n);
  WSALLOC(selfnorm, float, n);
  WSALLOC(csr_row, int, E);
  WSALLOC(csr_norm, float, E);
  WSALLOC(WT, short, 5 * 64 * 256);
  WSALLOC(Yc, float, sl128 * 5);
  WSALLOC(t0bf, unsigned, (size_t)n * 64);
  WSALLOC(tb0, unsigned, (size_t)n * 64);
  WSALLOC(tb1, unsigned, (size_t)n * 64);
  WSALLOC(u1, float, sl128);
  WSALLOC(emb_a, float, (size_t)n * F_OUT);
  WSALLOC(embBT, short, (size_t)128 * n);
  WSALLOC(vsum, float, sl128 * KSPLIT);
  WSALLOC(gbuf, float, sl128);
  (void)ws_size; (void)n_in; (void)out_size;

  hipMemsetAsync(deg, 0, (size_t)n * 4, stream);
  hipMemsetAsync(counts, 0, (size_t)n * 4, stream);

  int eb = (E + 255) / 256;
  hist_kernel<<<eb, 256, 0, stream>>>(ei, E, deg, counts);
  dis_kernel<<<(n + 255) / 256, 256, 0, stream>>>(deg, dis, selfnorm, n);
  scan_kernel<<<1, 1024, 0, stream>>>(counts, offs, cursors, n);
  fill_kernel<<<eb, 256, 0, stream>>>(ei, E, dis, cursors, csr_row, csr_norm);

  wt_kernel<<<(5 * 64 * 256 + 255) / 256, 256, 0, stream>>>(W, WT);
  fgemm_kernel<<<dim3(n / 16, 2), 64, 0, stream>>>(feat, feat_a, WT, Yc, (short*)t0bf, n);

  int gb = (n + 3) / 4;
  // Horner: u = Yc4(bf16); u = Yc3 + A u; ... ; u = Yc0 + A u (f32 final)
  gather_kernel<<<gb, 256, 0, stream>>>(Yc + 3 * sl128, t0bf, offs, csr_row, csr_norm, selfnorm, tb0, (float*)0, n, 0);
  gather_kernel<<<gb, 256, 0, stream>>>(Yc + 2 * sl128, tb0,  offs, csr_row, csr_norm, selfnorm, tb1, (float*)0, n, 0);
  gather_kernel<<<gb, 256, 0, stream>>>(Yc + 1 * sl128, tb1,  offs, csr_row, csr_norm, selfnorm, tb0, (float*)0, n, 0);
  gather_kernel<<<gb, 256, 0, stream>>>(Yc + 0 * sl128, tb0,  offs, csr_row, csr_norm, selfnorm, (unsigned*)0, u1, n, 1);
  relu_trans_kernel<<<(n + 63) / 64, 256, 0, stream>>>(u1, out, emb_a, embBT, n);

  readout_kernel<<<dim3((n + 63) / 64, KSPLIT), 256, 0, stream>>>(mask, embBT, vsum, n);
  gnorm_kernel<<<gb, 256, 0, stream>>>(vsum, gbuf, n);
  disc_kernel<<<gb, 256, 0, stream>>>(out, emb_a, gbuf, Wb, bsc, ret, reta, n);
}

// Round 6
// 452.323 us; speedup vs baseline: 1.6238x; 1.0104x over previous
//
#include <hip/hip_runtime.h>
#include <hip/hip_bf16.h>

typedef float f32x4 __attribute__((ext_vector_type(4)));
typedef short s16x8 __attribute__((ext_vector_type(8)));
typedef unsigned int u32x4 __attribute__((ext_vector_type(4)));

#define F_IN 256
#define F_OUT 64
#define KSPLIT 8

static __device__ __forceinline__ short f2bf(float f){  // RTNE
  union { float f; unsigned u; } x; x.f = f;
  unsigned r = (x.u + 0x7FFFu + ((x.u >> 16) & 1u)) >> 16;
  return (short)r;
}

static __device__ __forceinline__ unsigned pack_rtne(float f0, float f1){
  return ((unsigned)(unsigned short)f2bf(f0)) | ((unsigned)(unsigned short)f2bf(f1) << 16);
}

// truncation pack (bias cancels in L2-normalize downstream of the mask GEMM)
static __device__ __forceinline__ unsigned pack_trunc(float f0, float f1){
  return (__float_as_uint(f0) >> 16) | (__float_as_uint(f1) & 0xFFFF0000u);
}

static __device__ __forceinline__ float bf_lo(unsigned u){ return __uint_as_float(u << 16); }
static __device__ __forceinline__ float bf_hi(unsigned u){ return __uint_as_float(u & 0xFFFF0000u); }

union FragU { u32x4 u; s16x8 s; };

// ---------------- WT transpose-cast + zero deg/counts (replaces 2 memsets) ----------------

__global__ void wt_zero_kernel(const float* __restrict__ W, short* __restrict__ WT,
                               int* __restrict__ deg, int* __restrict__ counts, int n){
  int idx = blockIdx.x * blockDim.x + threadIdx.x;
  if (idx < n){ deg[idx] = 0; counts[idx] = 0; }
  if (idx < 5 * 64 * 256){
    int k = idx & 255, c = (idx >> 8) & 63, by = idx >> 14;
    WT[idx] = f2bf(W[(size_t)(by * 256 + k) * 64 + c]);
  }
}

// ---------------- degree / CSR build ----------------

__global__ void hist_kernel(const int* __restrict__ ei, int E, int* __restrict__ deg,
                            int* __restrict__ counts){
  int e = blockIdx.x * blockDim.x + threadIdx.x;
  if (e >= E) return;
  int r = ei[e], c = ei[E + e];
  if (r != c) atomicAdd(&deg[r], 1);
  atomicAdd(&counts[c], 1);
}

// scan of counts -> offsets/cursors, plus dis/selfnorm from deg (fused dis_kernel)
__global__ __launch_bounds__(1024) void scan_kernel(const int* __restrict__ counts,
                                                    const int* __restrict__ deg,
                                                    float* __restrict__ dis,
                                                    float* __restrict__ selfnorm,
                                                    int* __restrict__ offsets,
                                                    int* __restrict__ cursors, int n){
  const int C = 10;
  __shared__ int lds[1024];
  int tid = threadIdx.x;
  int base = tid * C;
  int s = 0;
  for (int i = 0; i < C; ++i){
    int idx = base + i;
    if (idx < n){
      s += counts[idx];
      float d = (float)(deg[idx] + 1);   // +1: appended self-loop
      dis[idx] = rsqrtf(d);
      selfnorm[idx] = 1.0f / d;
    }
  }
  lds[tid] = s; __syncthreads();
  for (int off = 1; off < 1024; off <<= 1){
    int add = (tid >= off) ? lds[tid - off] : 0;
    __syncthreads();
    lds[tid] += add;
    __syncthreads();
  }
  int run = lds[tid] - s;
  for (int i = 0; i < C; ++i){
    int idx = base + i;
    if (idx < n){ offsets[idx] = run; cursors[idx] = run; run += counts[idx]; }
  }
  if (tid == 1023) offsets[n] = lds[1023];
}

__global__ void fill_kernel(const int* __restrict__ ei, int E, const float* __restrict__ dis,
                            int* __restrict__ cursors, int* __restrict__ csr_row,
                            float* __restrict__ csr_norm){
  int e = blockIdx.x * blockDim.x + threadIdx.x;
  if (e >= E) return;
  int r = ei[e], c = ei[E + e];
  int pos = atomicAdd(&cursors[c], 1);
  csr_row[pos] = r;
  csr_norm[pos] = (r == c) ? 0.0f : dis[r] * dis[c];
}

// ---------------- feature GEMM: A-strip in regs, all 5 slabs per block ----------------
// Yc[by][M][128] f32 (z-half cols); also emits t0bf = bf16(Yc slab4). grid (M/16, 2).

__global__ __launch_bounds__(64) void fgemm_kernel(const float* __restrict__ X0,
                                                   const float* __restrict__ X1,
                                                   const short* __restrict__ WT,
                                                   float* __restrict__ Yc,
                                                   short* __restrict__ t0bf, int M){
  int bz = blockIdx.y;
  const float* X = bz ? X1 : X0;
  int l = threadIdx.x, lr = l & 15, g = l >> 4;
  int row0 = blockIdx.x * 16;
  const f32x4* ap = (const f32x4*)(X + (size_t)(row0 + lr) * F_IN + g * 8);
  s16x8 afr[8];
  #pragma unroll
  for (int it = 0; it < 8; ++it){
    f32x4 x0 = ap[it * 8], x1 = ap[it * 8 + 1];
    FragU af;
    af.u[0] = pack_rtne(x0[0], x0[1]); af.u[1] = pack_rtne(x0[2], x0[3]);
    af.u[2] = pack_rtne(x1[0], x1[1]); af.u[3] = pack_rtne(x1[2], x1[3]);
    afr[it] = af.s;
  }
  for (int by = 0; by < 5; ++by){
    f32x4 acc[4];
    #pragma unroll
    for (int ct = 0; ct < 4; ++ct) acc[ct] = (f32x4){0,0,0,0};
    const s16x8* bp[4];
    #pragma unroll
    for (int ct = 0; ct < 4; ++ct)
      bp[ct] = (const s16x8*)(WT + ((size_t)by * 64 + ct * 16 + lr) * F_IN + g * 8);
    #pragma unroll
    for (int it = 0; it < 8; ++it)
      #pragma unroll
      for (int ct = 0; ct < 4; ++ct)
        acc[ct] = __builtin_amdgcn_mfma_f32_16x16x32_bf16(afr[it], bp[ct][it * 4], acc[ct], 0, 0, 0);
    float* yp = Yc + (size_t)by * M * 128 + (size_t)bz * 64;
    #pragma unroll
    for (int ct = 0; ct < 4; ++ct)
      #pragma unroll
      for (int i = 0; i < 4; ++i){
        int grow = row0 + g * 4 + i;
        yp[(size_t)grow * 128 + ct * 16 + lr] = acc[ct][i];
        if (by == 4) t0bf[(size_t)grow * 128 + bz * 64 + ct * 16 + lr] = f2bf(acc[ct][i]);
      }
  }
}

// ---------------- sparse propagate (bf16 messages): tout = Yk + A * tin ----------------

__global__ __launch_bounds__(256) void gather_kernel(const float* __restrict__ Yk,
    const unsigned* __restrict__ tinb, const int* __restrict__ offsets,
    const int* __restrict__ csr_row, const float* __restrict__ csr_norm,
    const float* __restrict__ selfnorm, unsigned* __restrict__ toutb,
    float* __restrict__ toutf, int n, int wantf){
  int wid = threadIdx.x >> 6, lane = threadIdx.x & 63;
  int node = blockIdx.x * 4 + wid;
  if (node >= n) return;
  int e0 = offsets[node], e1 = offsets[node + 1];
  float sn = selfnorm[node];
  unsigned t0 = tinb[(size_t)node * 64 + lane];
  float2 yk = ((const float2*)Yk)[(size_t)node * 64 + lane];
  float ax = yk.x + sn * bf_lo(t0);
  float ay = yk.y + sn * bf_hi(t0);
  int i = e0;
  for (; i + 4 <= e1; i += 4){
    int r0 = csr_row[i], r1 = csr_row[i+1], r2 = csr_row[i+2], r3 = csr_row[i+3];
    float w0 = csr_norm[i], w1 = csr_norm[i+1], w2 = csr_norm[i+2], w3 = csr_norm[i+3];
    unsigned v0 = tinb[(size_t)r0 * 64 + lane];
    unsigned v1 = tinb[(size_t)r1 * 64 + lane];
    unsigned v2 = tinb[(size_t)r2 * 64 + lane];
    unsigned v3 = tinb[(size_t)r3 * 64 + lane];
    ax += w0 * bf_lo(v0); ay += w0 * bf_hi(v0);
    ax += w1 * bf_lo(v1); ay += w1 * bf_hi(v1);
    ax += w2 * bf_lo(v2); ay += w2 * bf_hi(v2);
    ax += w3 * bf_lo(v3); ay += w3 * bf_hi(v3);
  }
  for (; i < e1; ++i){
    unsigned v = tinb[(size_t)csr_row[i] * 64 + lane];
    float w = csr_norm[i];
    ax += w * bf_lo(v); ay += w * bf_hi(v);
  }
  if (wantf){
    float2 r; r.x = ax; r.y = ay;
    ((float2*)toutf)[(size_t)node * 64 + lane] = r;
  } else {
    toutb[(size_t)node * 64 + lane] = pack_rtne(ax, ay);
  }
}

// ---------------- relu + split + LDS-transpose bf16 pack ----------------

__global__ __launch_bounds__(256) void relu_trans_kernel(const float* __restrict__ u,
    float* __restrict__ emb, float* __restrict__ emb_a, short* __restrict__ embBT, int n){
  __shared__ short lds[128 * 72];
  int t = threadIdx.x;
  int node0 = blockIdx.x * 64;
  int nl = t >> 2;
  int f0 = (t & 3) * 32;
  int node = node0 + nl;
  if (node < n){
    const f32x4* up = (const f32x4*)(u + (size_t)node * 128 + f0);
    float* dst = (f0 < 64) ? (emb + (size_t)node * 64 + f0)
                           : (emb_a + (size_t)node * 64 + (f0 - 64));
    #pragma unroll
    for (int j4 = 0; j4 < 8; ++j4){
      f32x4 v = up[j4];
      #pragma unroll
      for (int e = 0; e < 4; ++e){
        float x = v[e] > 0.0f ? v[e] : 0.0f;
        v[e] = x;
        lds[(f0 + j4 * 4 + e) * 72 + nl] = f2bf(x);
      }
      ((f32x4*)dst)[j4] = v;
    }
  }
  __syncthreads();
  int f = t >> 1, c0 = (t & 1) * 32;
  short* op = embBT + (size_t)f * n + node0 + c0;
  const short* lp = lds + f * 72 + c0;
  if (node0 + 64 <= n){
    #pragma unroll
    for (int j = 0; j < 4; ++j)
      *(s16x8*)(op + j * 8) = *(const s16x8*)(lp + j * 8);
  } else {
    for (int j = 0; j < 32; ++j)
      if (node0 + c0 + j < n) op[j] = lp[j];
  }
}

// ---------------- readout GEMM: vsum[ks][n][128] partial = mask @ embBT^T ----------------
// global_load_lds double-buffered, counted-vmcnt pipeline (T3/T4), chunk-XOR swizzle
// via pre-swizzled global source + swizzled ds_read (rule 21). Tile 64x128xBK32.

__global__ __launch_bounds__(256, 4) void readout_kernel(const float* __restrict__ mask,
    const short* __restrict__ embBT, float* __restrict__ vsum, int n){
  __shared__ float Ab[2][64][32];   // logical [row][k], chunk-swizzled physically
  __shared__ short Bb[2][128][32];
  int t = threadIdx.x;
  int w = t >> 6, l = t & 63, lr = l & 15, g = l >> 4;
  int row0 = blockIdx.x * 64;
  int ks = blockIdx.y;

  int steps_total = (n + 31) >> 5;               // 313
  int per = steps_total / KSPLIT, rem = steps_total % KSPLIT;
  int sbeg = ks * per + (ks < rem ? ks : rem);
  int scnt = per + (ks < rem ? 1 : 0);
  bool tail = ((sbeg + scnt) == steps_total) && ((n & 31) != 0);
  int nf = scnt - (tail ? 1 : 0);
  int kb0 = sbeg << 5;

  // staging sources: linear LDS dest (lane*16B), source chunk pre-XOR'd
  int arow = row0 + w * 16 + (l >> 3);
  int aswz = ((l & 7) ^ ((l >> 3) & 7)) << 2;                 // float offset
  const float* asrc0 = mask + (size_t)min(arow,     n - 1) * n + aswz;
  const float* asrc1 = mask + (size_t)min(arow + 8, n - 1) * n + aswz;
  int bcol = w * 32 + (l >> 2);
  int bswz = ((l & 3) ^ ((l >> 3) & 3)) << 3;                 // short offset
  const short* bsrc0 = embBT + (size_t)bcol * n + bswz;
  const short* bsrc1 = embBT + (size_t)(bcol + 16) * n + bswz;

  #define GLDS(gp, lp) __builtin_amdgcn_global_load_lds( \
      (const __attribute__((address_space(1))) void*)(const void*)(gp), \
      (__attribute__((address_space(3))) void*)(void*)(lp), 16, 0, 0)
  #define STAGE(kb, bi) do{ \
    GLDS(asrc0 + (kb), &Ab[bi][w * 16     ][0]); \
    GLDS(asrc1 + (kb), &Ab[bi][w * 16 +  8][0]); \
    GLDS(bsrc0 + (kb), &Bb[bi][w * 32     ][0]); \
    GLDS(bsrc1 + (kb), &Bb[bi][w * 32 + 16][0]); \
  }while(0)

  f32x4 acc[8];
  #pragma unroll
  for (int ct = 0; ct < 8; ++ct) acc[ct] = (f32x4){0,0,0,0};

  if (nf > 0) STAGE(kb0, 0);
  if (nf > 1) STAGE(kb0 + 32, 1);

  for (int s = 0; s < nf; ++s){
    if (s + 1 < nf) asm volatile("s_waitcnt vmcnt(4)" ::: "memory");
    else            asm volatile("s_waitcnt vmcnt(0)" ::: "memory");
    __builtin_amdgcn_s_barrier();
    int cur = s & 1;
    f32x4 x0 = *(const f32x4*)&Ab[cur][w * 16 + lr][((2 * g)     ^ (lr & 7)) << 2];
    f32x4 x1 = *(const f32x4*)&Ab[cur][w * 16 + lr][((2 * g + 1) ^ (lr & 7)) << 2];
    FragU af;
    af.u[0] = pack_trunc(x0[0], x0[1]); af.u[1] = pack_trunc(x0[2], x0[3]);
    af.u[2] = pack_trunc(x1[0], x1[1]); af.u[3] = pack_trunc(x1[2], x1[3]);
    #pragma unroll
    for (int ct = 0; ct < 8; ++ct){
      s16x8 bf = *(const s16x8*)&Bb[cur][ct * 16 + lr][(g ^ ((lr >> 1) & 3)) << 3];
      acc[ct] = __builtin_amdgcn_mfma_f32_16x16x32_bf16(af.s, bf, acc[ct], 0, 0, 0);
    }
    asm volatile("s_waitcnt lgkmcnt(0)" ::: "memory");
    __builtin_amdgcn_s_barrier();
    if (s + 2 < nf) STAGE(kb0 + (s + 2) * 32, cur);
  }
  #undef STAGE
  #undef GLDS

  if (tail){
    int kb = kb0 + nf * 32;
    int kleft = n - kb;                          // 16
    FragU af; af.u = (u32x4){0,0,0,0};
    const s16x8 bz = {0,0,0,0,0,0,0,0};
    s16x8 bf[8];
    #pragma unroll
    for (int ct = 0; ct < 8; ++ct) bf[ct] = bz;
    int r = row0 + w * 16 + lr;
    if (g * 8 < kleft){
      if (r < n){
        const f32x4* p = (const f32x4*)(mask + (size_t)r * n + kb + g * 8);
        f32x4 r0 = p[0], r1 = p[1];
        af.u[0] = pack_trunc(r0[0], r0[1]); af.u[1] = pack_trunc(r0[2], r0[3]);
        af.u[2] = pack_trunc(r1[0], r1[1]); af.u[3] = pack_trunc(r1[2], r1[3]);
      }
      #pragma unroll
      for (int ct = 0; ct < 8; ++ct)
        bf[ct] = *(const s16x8*)(embBT + (size_t)(ct * 16 + lr) * n + kb + g * 8);
    }
    #pragma unroll
    for (int ct = 0; ct < 8; ++ct)
      acc[ct] = __builtin_amdgcn_mfma_f32_16x16x32_bf16(af.s, bf[ct], acc[ct], 0, 0, 0);
  }

  float* vs = vsum + (size_t)ks * n * 128;
  int rbase = row0 + w * 16;
  #pragma unroll
  for (int ct = 0; ct < 8; ++ct)
    #pragma unroll
    for (int i = 0; i < 4; ++i){
      int gr = rbase + g * 4 + i;
      if (gr < n) vs[(size_t)gr * 128 + ct * 16 + lr] = acc[ct][i];
    }
}

// ---------------- fused: g = sigmoid(v/||v||) (K-split sum) + bilinear discriminator ----------------

__global__ __launch_bounds__(256) void gnorm_disc_kernel(const float* __restrict__ vsum,
    const float* __restrict__ emb, const float* __restrict__ emb_a,
    const float* __restrict__ Wb, const float* __restrict__ bptr,
    float* __restrict__ ret, float* __restrict__ reta, int n){
  __shared__ float Wl[64][65];
  int t = threadIdx.x;
  for (int i = t; i < 4096; i += 256) Wl[i >> 6][i & 63] = Wb[i];
  __syncthreads();
  int wid = t >> 6, lane = t & 63;
  int node = blockIdx.x * 4 + wid;
  if (node >= n) return;

  // gnorm part
  size_t stride = (size_t)n * 128;
  float v1 = 0.0f, v2 = 0.0f;
  #pragma unroll
  for (int ks = 0; ks < KSPLIT; ++ks){
    v1 += vsum[ks * stride + (size_t)node * 128 + lane];
    v2 += vsum[ks * stride + (size_t)node * 128 + 64 + lane];
  }
  float s1 = v1 * v1, s2 = v2 * v2;
  for (int off = 32; off >= 1; off >>= 1){
    s1 += __shfl_xor(s1, off);
    s2 += __shfl_xor(s2, off);
  }
  float i1 = v1 / fmaxf(sqrtf(s1), 1e-12f);
  float i2 = v2 / fmaxf(sqrtf(s2), 1e-12f);
  float g1 = 1.0f / (1.0f + expf(-i1));
  float g2 = 1.0f / (1.0f + expf(-i2));

  // disc part
  float e1 = emb[(size_t)node * 64 + lane];
  float e2 = emb_a[(size_t)node * 64 + lane];
  float u1 = 0.0f, u2 = 0.0f;
  for (int e = 0; e < 64; ++e){
    float wv = Wl[lane][e];
    u1 += wv * __shfl(g1, e);
    u2 += wv * __shfl(g2, e);
  }
  float p1 = e1 * u1, p2 = e2 * u1, p3 = e2 * u2, p4 = e1 * u2;
  for (int off = 32; off >= 1; off >>= 1){
    p1 += __shfl_xor(p1, off); p2 += __shfl_xor(p2, off);
    p3 += __shfl_xor(p3, off); p4 += __shfl_xor(p4, off);
  }
  if (lane == 0){
    float b = bptr[0];
    ret[(size_t)node * 2 + 0]  = p1 + b;
    ret[(size_t)node * 2 + 1]  = p2 + b;
    reta[(size_t)node * 2 + 0] = p3 + b;
    reta[(size_t)node * 2 + 1] = p4 + b;
  }
}

// ---------------- launch ----------------

extern "C" void kernel_launch(void* const* d_in, const int* in_sizes, int n_in,
                              void* d_out, int out_size, void* d_ws, size_t ws_size,
                              hipStream_t stream) {
  const float* feat   = (const float*)d_in[0];
  const float* feat_a = (const float*)d_in[1];
  const int*   ei     = (const int*)d_in[2];
  const float* mask   = (const float*)d_in[3];
  const float* W      = (const float*)d_in[4];
  const float* Wb     = (const float*)d_in[5];
  const float* bsc    = (const float*)d_in[6];
  const int n = in_sizes[0] / F_IN;      // 10000
  const int E = in_sizes[2] / 2;         // 640000
  const size_t sl128 = (size_t)n * 128;

  float* out  = (float*)d_out;
  float* ret  = out + (size_t)n * F_OUT;
  float* reta = ret + (size_t)n * 2;

  char* wsb = (char*)d_ws;
  size_t off = 0;
  #define WSALLOC(ptr, T, cnt) T* ptr = (T*)(wsb + off); off = (off + sizeof(T)*(size_t)(cnt) + 255) & ~(size_t)255
  WSALLOC(deg, int, n);
  WSALLOC(counts, int, n);
  WSALLOC(offs, int, n + 1);
  WSALLOC(cursors, int, n);
  WSALLOC(dis, float, n);
  WSALLOC(selfnorm, float, n);
  WSALLOC(csr_row, int, E);
  WSALLOC(csr_norm, float, E);
  WSALLOC(WT, short, 5 * 64 * 256);
  WSALLOC(Yc, float, sl128 * 5);
  WSALLOC(t0bf, unsigned, (size_t)n * 64);
  WSALLOC(tb0, unsigned, (size_t)n * 64);
  WSALLOC(tb1, unsigned, (size_t)n * 64);
  WSALLOC(u1, float, sl128);
  WSALLOC(emb_a, float, (size_t)n * F_OUT);
  WSALLOC(embBT, short, (size_t)128 * n);
  WSALLOC(vsum, float, sl128 * KSPLIT);
  (void)ws_size; (void)n_in; (void)out_size;

  int eb = (E + 255) / 256;
  wt_zero_kernel<<<(5 * 64 * 256 + 255) / 256, 256, 0, stream>>>(W, WT, deg, counts, n);
  hist_kernel<<<eb, 256, 0, stream>>>(ei, E, deg, counts);
  scan_kernel<<<1, 1024, 0, stream>>>(counts, deg, dis, selfnorm, offs, cursors, n);
  fill_kernel<<<eb, 256, 0, stream>>>(ei, E, dis, cursors, csr_row, csr_norm);

  fgemm_kernel<<<dim3(n / 16, 2), 64, 0, stream>>>(feat, feat_a, WT, Yc, (short*)t0bf, n);

  int gb = (n + 3) / 4;
  // Horner: u = Yc4(bf16); u = Yc3 + A u; ... ; u = Yc0 + A u (f32 final)
  gather_kernel<<<gb, 256, 0, stream>>>(Yc + 3 * sl128, t0bf, offs, csr_row, csr_norm, selfnorm, tb0, (float*)0, n, 0);
  gather_kernel<<<gb, 256, 0, stream>>>(Yc + 2 * sl128, tb0,  offs, csr_row, csr_norm, selfnorm, tb1, (float*)0, n, 0);
  gather_kernel<<<gb, 256, 0, stream>>>(Yc + 1 * sl128, tb1,  offs, csr_row, csr_norm, selfnorm, tb0, (float*)0, n, 0);
  gather_kernel<<<gb, 256, 0, stream>>>(Yc + 0 * sl128, tb0,  offs, csr_row, csr_norm, selfnorm, (unsigned*)0, u1, n, 1);
  relu_trans_kernel<<<(n + 63) / 64, 256, 0, stream>>>(u1, out, emb_a, embBT, n);

  readout_kernel<<<dim3((n + 63) / 64, KSPLIT), 256, 0, stream>>>(mask, embBT, vsum, n);
  gnorm_disc_kernel<<<gb, 256, 0, stream>>>(vsum, out, emb_a, Wb, bsc, ret, reta, n);
}